// Round 14
// baseline (121.264 us; speedup 1.0000x reference)
//
#include <hip/hip_runtime.h>
#include <math.h>

// problem constants
constexpr int BB   = 2;
constexpr int NN   = 4096;
constexpr int CCH  = 256;   // channels
constexpr int NH   = 8;     // heads
constexpr int HD   = 32;    // head dim
constexpr int GW   = 64;    // spatial h = w
constexpr int NKV  = 1024;  // (64/2)*(64/2)
constexpr int HIDN = 1024;
constexpr float EPSF = 1e-5f;

typedef short  bf16x8 __attribute__((ext_vector_type(8)));
typedef short  bf16x4 __attribute__((ext_vector_type(4)));
typedef float  f32x4  __attribute__((ext_vector_type(4)));

__device__ __forceinline__ short f2bf(float f) {
    unsigned int u = __float_as_uint(f);
    unsigned int r = (u + 0x7FFFu + ((u >> 16) & 1u)) >> 16;   // RNE
    return (short)r;
}
__device__ __forceinline__ float bf2f(short s) {
    return __uint_as_float(((unsigned int)(unsigned short)s) << 16);
}
// packed f32x2 -> bf16x2 (RNE), src0 -> low half
__device__ __forceinline__ unsigned int cvtpk_bf16(float a, float b) {
    unsigned int r;
    asm("v_cvt_pk_bf16_f32 %0, %1, %2" : "=v"(r) : "v"(a), "v"(b));
    return r;
}
// async global->LDS, 16B per lane; lds base must be wave-uniform (HW adds lane*16)
__device__ __forceinline__ void gl16(const void* g, void* l) {
    __builtin_amdgcn_global_load_lds(
        (const __attribute__((address_space(1))) void*)g,
        (__attribute__((address_space(3))) void*)l, 16, 0, 0);
}

// ---------------- prep: weight cvt (blocks 0..4095) + LN1 (blocks 4096..12287) ----------------
// sr_w reordered: srwb[o][q*256+c] = sr_w[o][c*4+q]  (K-dim quad-major)
__global__ __launch_bounds__(256) void prep_kernel(const float* __restrict__ q_w,
                                                   const float* __restrict__ kv_w,
                                                   const float* __restrict__ proj_w,
                                                   const float* __restrict__ fc1_w,
                                                   const float* __restrict__ fc2_w,
                                                   const float* __restrict__ sr_w,
                                                   short* qwb, short* kvwb, short* pjwb,
                                                   short* f1wb, short* f2wb, short* srwb,
                                                   const float* __restrict__ x,
                                                   const float* __restrict__ ln1_g,
                                                   const float* __restrict__ ln1_b,
                                                   short* __restrict__ xn) {
    __shared__ float pa[4], pb[4];
    int t = threadIdx.x;
    if (blockIdx.x < 4096) {
        int i = blockIdx.x * 256 + t;
        if (i < 65536) { qwb[i] = f2bf(q_w[i] * 0.17677669529663687f); return; }
        i -= 65536;
        if (i < 131072) { kvwb[i] = f2bf(kv_w[i]); return; }
        i -= 131072;
        if (i < 65536) { pjwb[i] = f2bf(proj_w[i]); return; }
        i -= 65536;
        if (i < 262144) { f1wb[i] = f2bf(fc1_w[i]); return; }
        i -= 262144;
        if (i < 262144) { f2wb[i] = f2bf(fc2_w[i]); return; }
        i -= 262144;
        {
            int o = i >> 10, rem = i & 1023, c = rem >> 2, q = rem & 3;
            srwb[o * 1024 + q * 256 + c] = f2bf(sr_w[i]);
        }
        return;
    }
    int row = blockIdx.x - 4096;
    float v = x[row * CCH + t];
    float a = v, b = v * v;
#pragma unroll
    for (int off = 32; off > 0; off >>= 1) {
        a += __shfl_xor(a, off);
        b += __shfl_xor(b, off);
    }
    int w = t >> 6;
    if ((t & 63) == 0) { pa[w] = a; pb[w] = b; }
    __syncthreads();
    a = pa[0] + pa[1] + pa[2] + pa[3];
    b = pb[0] + pb[1] + pb[2] + pb[3];
    float mu = a * (1.0f / CCH);
    float var = b * (1.0f / CCH) - mu * mu;
    float rs = rsqrtf(var + EPSF);
    xn[row * CCH + t] = f2bf((v - mu) * rs * ln1_g[t] + ln1_b[t]);
}

// ---------------- gemm64 body (device fn): 64x64 tile, BK=64, 2-phase dbuf ----------------
template <bool OUTB, int RESMODE>
__device__ __forceinline__ void gemm64_body(const short* __restrict__ A,
                                            const short* __restrict__ W,
                                            const float* __restrict__ bias,
                                            const void* __restrict__ res,
                                            void* __restrict__ outp,
                                            int M, int O, int K, int bx, int by,
                                            short (*As0)[64], short (*Ws0)[64],
                                            short (*As1)[64], short (*Ws1)[64]) {
    int t = threadIdx.x;
    int m0 = by * 64, o0 = bx * 64;
    int w = t >> 6, lane = t & 63;
    int wm = (w >> 1) * 32, wn = (w & 1) * 32;
    int fr = lane & 15, fq = lane >> 4;
    int srow = lane >> 3;
    int sg   = (lane & 7) ^ srow;
    f32x4 acc[2][2];
#pragma unroll
    for (int mi = 0; mi < 2; mi++)
#pragma unroll
        for (int ni = 0; ni < 2; ni++)
            acc[mi][ni] = f32x4{0.f, 0.f, 0.f, 0.f};

    auto stage = [&](short (*Asb)[64], short (*Wsb)[64], int k0) {
#pragma unroll
        for (int r = 0; r < 2; r++) {
            int rowA = r * 32 + w * 8 + srow;
            gl16(&A[(size_t)(m0 + rowA) * K + k0 + sg * 8], &Asb[r * 32 + w * 8][0]);
            gl16(&W[(size_t)(o0 + rowA) * K + k0 + sg * 8], &Wsb[r * 32 + w * 8][0]);
        }
    };
    auto compute = [&](short (*Asb)[64], short (*Wsb)[64]) {
#pragma unroll
        for (int half = 0; half < 2; half++) {
            bf16x8 af[2], wf[2];
#pragma unroll
            for (int mi = 0; mi < 2; mi++) {
                int row = wm + mi * 16 + fr;
                af[mi] = *(const bf16x8*)&Asb[row][(((half << 2) | fq) ^ (row & 7)) * 8];
            }
#pragma unroll
            for (int ni = 0; ni < 2; ni++) {
                int row = wn + ni * 16 + fr;
                wf[ni] = *(const bf16x8*)&Wsb[row][(((half << 2) | fq) ^ (row & 7)) * 8];
            }
#pragma unroll
            for (int mi = 0; mi < 2; mi++)
#pragma unroll
                for (int ni = 0; ni < 2; ni++)
                    acc[mi][ni] = __builtin_amdgcn_mfma_f32_16x16x32_bf16(
                        af[mi], wf[ni], acc[mi][ni], 0, 0, 0);
        }
    };

    stage(As0, Ws0, 0);
    __syncthreads();
    for (int k0 = 0; k0 < K; k0 += 128) {
        if (k0 + 64 < K) stage(As1, Ws1, k0 + 64);
        compute(As0, Ws0);
        __syncthreads();
        if (k0 + 128 < K) stage(As0, Ws0, k0 + 128);
        if (k0 + 64 < K) compute(As1, Ws1);
        __syncthreads();
    }
#pragma unroll
    for (int mi = 0; mi < 2; mi++)
#pragma unroll
        for (int ni = 0; ni < 2; ni++)
#pragma unroll
            for (int r = 0; r < 4; r++) {
                int m = m0 + wm + mi * 16 + fq * 4 + r;
                int o = o0 + wn + ni * 16 + fr;
                float v = acc[mi][ni][r];
                if (bias) v += bias[o];
                if (RESMODE == 1) v += ((const float*)res)[(size_t)m * O + o];
                if (RESMODE == 2) v += bf2f(((const short*)res)[(size_t)m * O + o]);
                if (OUTB) ((short*)outp)[(size_t)m * O + o] = f2bf(v);
                else      ((float*)outp)[(size_t)m * O + o] = v;
            }
}

// standalone gemm64 kernel (proj, fc2)
template <bool OUTB, int RESMODE>
__global__ __launch_bounds__(256, 4) void gemm64(const short* __restrict__ A,
                                                 const short* __restrict__ W,
                                                 const float* __restrict__ bias,
                                                 const void* __restrict__ res,
                                                 void* __restrict__ outp,
                                                 int M, int O, int K) {
    __shared__ short As0[64][64], Ws0[64][64];
    __shared__ short As1[64][64], Ws1[64][64];
    gemm64_body<OUTB, RESMODE>(A, W, bias, res, outp, M, O, K,
                               blockIdx.x, blockIdx.y, As0, Ws0, As1, Ws1);
}

// ---------------- SR conv body: fused im2col gather (K reordered: k = q*256+c) ----------------
__device__ __forceinline__ void sr_body(const short* __restrict__ xn,
                                        const short* __restrict__ Wsr,
                                        const float* __restrict__ sr_b,
                                        float* __restrict__ srtmp, int bx, int by,
                                        short (*As0)[64], short (*As1)[64],
                                        short (*Ws0)[64], short (*Ws1)[64]) {
    int t = threadIdx.x;
    int m0 = by * 32, o0 = bx * 64;
    int w = t >> 6, lane = t & 63;
    int wm = (w >> 1) * 16, wn = (w & 1) * 32;
    int fr = lane & 15, fq = lane >> 4;
    int srow = lane >> 3;
    int sg   = (lane & 7) ^ srow;
    int arow = w * 8 + srow;
    int p = m0 + arow;
    int b = p >> 10, pp = p & 1023, ii = pp >> 5, jj = pp & 31;
    int nbase = ii * 128 + jj * 2;
    size_t xbase = (size_t)(b * NN) * CCH;
    f32x4 acc[2];
    acc[0] = f32x4{0.f, 0.f, 0.f, 0.f};
    acc[1] = f32x4{0.f, 0.f, 0.f, 0.f};

    auto stage = [&](short (*Asb)[64], short (*Wsb)[64], int k0) {
        int q = k0 >> 8, c0 = k0 & 255;
        int n = nbase + (q >> 1) * 64 + (q & 1);
        gl16(&xn[xbase + (size_t)n * CCH + c0 + sg * 8], &Asb[w * 8][0]);
#pragma unroll
        for (int r = 0; r < 2; r++)
            gl16(&Wsr[(size_t)(o0 + r * 32 + w * 8 + srow) * 1024 + k0 + sg * 8],
                 &Wsb[r * 32 + w * 8][0]);
    };
    auto compute = [&](short (*Asb)[64], short (*Wsb)[64]) {
#pragma unroll
        for (int half = 0; half < 2; half++) {
            int cg = (half << 2) | fq;
            int rowa = wm + fr;
            bf16x8 af = *(const bf16x8*)&Asb[rowa][(cg ^ (rowa & 7)) * 8];
            bf16x8 wf[2];
#pragma unroll
            for (int ni = 0; ni < 2; ni++) {
                int row = wn + ni * 16 + fr;
                wf[ni] = *(const bf16x8*)&Wsb[row][(cg ^ (row & 7)) * 8];
            }
#pragma unroll
            for (int ni = 0; ni < 2; ni++)
                acc[ni] = __builtin_amdgcn_mfma_f32_16x16x32_bf16(
                    af, wf[ni], acc[ni], 0, 0, 0);
        }
    };

    stage(As0, Ws0, 0);
    __syncthreads();
    for (int k0 = 0; k0 < 1024; k0 += 128) {
        if (k0 + 64 < 1024) stage(As1, Ws1, k0 + 64);
        compute(As0, Ws0);
        __syncthreads();
        if (k0 + 128 < 1024) stage(As0, Ws0, k0 + 128);
        compute(As1, Ws1);
        __syncthreads();
    }
#pragma unroll
    for (int ni = 0; ni < 2; ni++)
#pragma unroll
        for (int r = 0; r < 4; r++) {
            int m = m0 + wm + fq * 4 + r;
            int o = o0 + wn + ni * 16 + fr;
            srtmp[(size_t)m * CCH + o] = acc[ni][r] + sr_b[o];
        }
}

// ---------------- merged q-GEMM (blocks 0..511) + sr-GEMM (blocks 512..767) ----------------
__global__ __launch_bounds__(256, 4) void qsr_gemm(const short* __restrict__ xn,
                                                   const short* __restrict__ qwb,
                                                   short* __restrict__ qb,
                                                   const short* __restrict__ srwb,
                                                   const float* __restrict__ sr_b,
                                                   float* __restrict__ srtmp) {
    __shared__ short pool[16384];   // 32 KB
    int i = blockIdx.x;
    if (i < 512) {
        gemm64_body<true, 0>(xn, qwb, nullptr, nullptr, qb, BB * NN, CCH, CCH,
                             i & 3, i >> 2,
                             (short(*)[64])(pool),
                             (short(*)[64])(pool + 4096),
                             (short(*)[64])(pool + 8192),
                             (short(*)[64])(pool + 12288));
    } else {
        i -= 512;
        sr_body(xn, srwb, sr_b, srtmp, i & 3, i >> 2,
                (short(*)[64])(pool),
                (short(*)[64])(pool + 2048),
                (short(*)[64])(pool + 4096),
                (short(*)[64])(pool + 8192));
    }
}

// ---------------- kvln_gemm: fused LN(srn) + kv GEMM + V-transpose epilogue ----------------
// A rows LN'ed from f32 srtmp into LDS [64][280] (pad -> 2-way max); W staged gl16 dbuf.
__global__ __launch_bounds__(256, 3) void kvln_gemm(const float* __restrict__ srtmp,
                                                    const float* __restrict__ srn_g,
                                                    const float* __restrict__ srn_b,
                                                    const short* __restrict__ W,
                                                    short* __restrict__ kvk,
                                                    short* __restrict__ vt) {
    __shared__ short Als[64][280];
    __shared__ short Ws0[64][64], Ws1[64][64];
    int t = threadIdx.x;
    int m0 = blockIdx.y * 64, o0 = blockIdx.x * 64;
    int w = t >> 6, lane = t & 63;
    int wm = (w >> 1) * 32, wn = (w & 1) * 32;
    int fr = lane & 15, fq = lane >> 4;
    int srow = lane >> 3;
    int sg   = (lane & 7) ^ srow;
    // ---- LN phase: 4 rows in parallel per pass (16 lanes per row), 4 passes/wave ----
    {
        int cl = lane & 15, rq = lane >> 4;
        float4 gg0 = *(const float4*)&srn_g[cl * 16];
        float4 gg1 = *(const float4*)&srn_g[cl * 16 + 4];
        float4 gg2 = *(const float4*)&srn_g[cl * 16 + 8];
        float4 gg3 = *(const float4*)&srn_g[cl * 16 + 12];
        float4 bb0 = *(const float4*)&srn_b[cl * 16];
        float4 bb1 = *(const float4*)&srn_b[cl * 16 + 4];
        float4 bb2 = *(const float4*)&srn_b[cl * 16 + 8];
        float4 bb3 = *(const float4*)&srn_b[cl * 16 + 12];
#pragma unroll
        for (int pass = 0; pass < 4; pass++) {
            int row = w * 16 + pass * 4 + rq;
            const float* src = &srtmp[(size_t)(m0 + row) * CCH + cl * 16];
            float4 v0 = *(const float4*)&src[0];
            float4 v1 = *(const float4*)&src[4];
            float4 v2 = *(const float4*)&src[8];
            float4 v3 = *(const float4*)&src[12];
            float a = (v0.x + v0.y + v0.z + v0.w) + (v1.x + v1.y + v1.z + v1.w)
                    + (v2.x + v2.y + v2.z + v2.w) + (v3.x + v3.y + v3.z + v3.w);
            float b = (v0.x*v0.x + v0.y*v0.y + v0.z*v0.z + v0.w*v0.w)
                    + (v1.x*v1.x + v1.y*v1.y + v1.z*v1.z + v1.w*v1.w)
                    + (v2.x*v2.x + v2.y*v2.y + v2.z*v2.z + v2.w*v2.w)
                    + (v3.x*v3.x + v3.y*v3.y + v3.z*v3.z + v3.w*v3.w);
#pragma unroll
            for (int off = 1; off < 16; off <<= 1) {
                a += __shfl_xor(a, off);
                b += __shfl_xor(b, off);
            }
            float mu = a * (1.0f / CCH);
            float var = b * (1.0f / CCH) - mu * mu;
            float rs = rsqrtf(var + EPSF);
            bf16x4 o0v, o1v, o2v, o3v;
            o0v[0]=f2bf((v0.x-mu)*rs*gg0.x+bb0.x); o0v[1]=f2bf((v0.y-mu)*rs*gg0.y+bb0.y);
            o0v[2]=f2bf((v0.z-mu)*rs*gg0.z+bb0.z); o0v[3]=f2bf((v0.w-mu)*rs*gg0.w+bb0.w);
            o1v[0]=f2bf((v1.x-mu)*rs*gg1.x+bb1.x); o1v[1]=f2bf((v1.y-mu)*rs*gg1.y+bb1.y);
            o1v[2]=f2bf((v1.z-mu)*rs*gg1.z+bb1.z); o1v[3]=f2bf((v1.w-mu)*rs*gg1.w+bb1.w);
            o2v[0]=f2bf((v2.x-mu)*rs*gg2.x+bb2.x); o2v[1]=f2bf((v2.y-mu)*rs*gg2.y+bb2.y);
            o2v[2]=f2bf((v2.z-mu)*rs*gg2.z+bb2.z); o2v[3]=f2bf((v2.w-mu)*rs*gg2.w+bb2.w);
            o3v[0]=f2bf((v3.x-mu)*rs*gg3.x+bb3.x); o3v[1]=f2bf((v3.y-mu)*rs*gg3.y+bb3.y);
            o3v[2]=f2bf((v3.z-mu)*rs*gg3.z+bb3.z); o3v[3]=f2bf((v3.w-mu)*rs*gg3.w+bb3.w);
            *(bf16x4*)&Als[row][cl * 16]      = o0v;
            *(bf16x4*)&Als[row][cl * 16 + 4]  = o1v;
            *(bf16x4*)&Als[row][cl * 16 + 8]  = o2v;
            *(bf16x4*)&Als[row][cl * 16 + 12] = o3v;
        }
    }
    // ---- GEMM phase: A from Als (plain), W staged+swizzled ----
    f32x4 acc[2][2];
#pragma unroll
    for (int mi = 0; mi < 2; mi++)
#pragma unroll
        for (int ni = 0; ni < 2; ni++)
            acc[mi][ni] = f32x4{0.f, 0.f, 0.f, 0.f};
    auto stageW = [&](short (*Wsb)[64], int k0) {
#pragma unroll
        for (int r = 0; r < 2; r++)
            gl16(&W[(size_t)(o0 + r * 32 + w * 8 + srow) * CCH + k0 + sg * 8],
                 &Wsb[r * 32 + w * 8][0]);
    };
    auto compute = [&](int k0, short (*Wsb)[64]) {
#pragma unroll
        for (int half = 0; half < 2; half++) {
            int cg = (half << 2) | fq;
            bf16x8 af[2], wf[2];
#pragma unroll
            for (int mi = 0; mi < 2; mi++)
                af[mi] = *(const bf16x8*)&Als[wm + mi * 16 + fr][k0 + cg * 8];
#pragma unroll
            for (int ni = 0; ni < 2; ni++) {
                int row = wn + ni * 16 + fr;
                wf[ni] = *(const bf16x8*)&Wsb[row][(cg ^ (row & 7)) * 8];
            }
#pragma unroll
            for (int mi = 0; mi < 2; mi++)
#pragma unroll
                for (int ni = 0; ni < 2; ni++)
                    acc[mi][ni] = __builtin_amdgcn_mfma_f32_16x16x32_bf16(
                        af[mi], wf[ni], acc[mi][ni], 0, 0, 0);
        }
    };
    stageW(Ws0, 0);
    __syncthreads();          // Als ready + Ws0 ready
    stageW(Ws1, 64);
    compute(0, Ws0);
    __syncthreads();
    stageW(Ws0, 128);
    compute(64, Ws1);
    __syncthreads();
    stageW(Ws1, 192);
    compute(128, Ws0);
    __syncthreads();
    compute(192, Ws1);
    // ---- epilogue: kvk + permuted vt ----
#pragma unroll
    for (int mi = 0; mi < 2; mi++)
#pragma unroll
        for (int ni = 0; ni < 2; ni++) {
            int o = o0 + wn + ni * 16 + fr;
            int mbase = m0 + wm + mi * 16 + fq * 4;
            if (o < 256) {
#pragma unroll
                for (int r = 0; r < 4; r++)
                    kvk[(size_t)(mbase + r) * 256 + o] = f2bf(acc[mi][ni][r]);
            } else {
                int h = (o - 256) >> 5, d = (o - 256) & 31;
                int b = mbase >> 10, y0 = mbase & 1023;
                size_t rowbase = ((size_t)((b * NH + h) * HD) + d) * NKV + (y0 >> 6) * 64;
                int y4 = y0 & 63;
#pragma unroll
                for (int r = 0; r < 4; r++) {
                    int y64 = y4 + r;
                    int s = (y64 & 15) * 4 + (y64 >> 4);
                    vt[rowbase + s] = f2bf(acc[mi][ni][r]);
                }
            }
        }
}

// ---------------- fc1ln_gemm: fused LN2 + fc1 (64x128 tile, acc[2][4]) ----------------
__global__ __launch_bounds__(256, 2) void fc1ln_gemm(const short* __restrict__ x1,
                                                     const float* __restrict__ ln2_g,
                                                     const float* __restrict__ ln2_b,
                                                     const short* __restrict__ W,
                                                     const float* __restrict__ bias,
                                                     short* __restrict__ outp) {
    __shared__ short Als[64][280];
    __shared__ short Ws0[128][64], Ws1[128][64];
    int t = threadIdx.x;
    int m0 = blockIdx.y * 64, o0 = blockIdx.x * 128;
    int w = t >> 6, lane = t & 63;
    int wm = (w >> 1) * 32, wn = (w & 1) * 64;
    int fr = lane & 15, fq = lane >> 4;
    int srow = lane >> 3;
    int sg   = (lane & 7) ^ srow;
    // ---- LN phase (bf16 input) ----
    {
        int cl = lane & 15, rq = lane >> 4;
        float4 gg0 = *(const float4*)&ln2_g[cl * 16];
        float4 gg1 = *(const float4*)&ln2_g[cl * 16 + 4];
        float4 gg2 = *(const float4*)&ln2_g[cl * 16 + 8];
        float4 gg3 = *(const float4*)&ln2_g[cl * 16 + 12];
        float4 bb0 = *(const float4*)&ln2_b[cl * 16];
        float4 bb1 = *(const float4*)&ln2_b[cl * 16 + 4];
        float4 bb2 = *(const float4*)&ln2_b[cl * 16 + 8];
        float4 bb3 = *(const float4*)&ln2_b[cl * 16 + 12];
#pragma unroll
        for (int pass = 0; pass < 4; pass++) {
            int row = w * 16 + pass * 4 + rq;
            const short* src = &x1[(size_t)(m0 + row) * CCH + cl * 16];
            bf16x8 u0 = *(const bf16x8*)&src[0];
            bf16x8 u1 = *(const bf16x8*)&src[8];
            float v[16];
#pragma unroll
            for (int j = 0; j < 8; j++) { v[j] = bf2f(u0[j]); v[8 + j] = bf2f(u1[j]); }
            float a = 0.f, b = 0.f;
#pragma unroll
            for (int j = 0; j < 16; j++) { a += v[j]; b += v[j] * v[j]; }
#pragma unroll
            for (int off = 1; off < 16; off <<= 1) {
                a += __shfl_xor(a, off);
                b += __shfl_xor(b, off);
            }
            float mu = a * (1.0f / CCH);
            float var = b * (1.0f / CCH) - mu * mu;
            float rs = rsqrtf(var + EPSF);
            float g4[16] = {gg0.x, gg0.y, gg0.z, gg0.w, gg1.x, gg1.y, gg1.z, gg1.w,
                            gg2.x, gg2.y, gg2.z, gg2.w, gg3.x, gg3.y, gg3.z, gg3.w};
            float b4[16] = {bb0.x, bb0.y, bb0.z, bb0.w, bb1.x, bb1.y, bb1.z, bb1.w,
                            bb2.x, bb2.y, bb2.z, bb2.w, bb3.x, bb3.y, bb3.z, bb3.w};
            bf16x8 w0, w1;
#pragma unroll
            for (int j = 0; j < 8; j++) {
                w0[j] = f2bf((v[j] - mu) * rs * g4[j] + b4[j]);
                w1[j] = f2bf((v[8 + j] - mu) * rs * g4[8 + j] + b4[8 + j]);
            }
            *(bf16x8*)&Als[row][cl * 16]     = w0;
            *(bf16x8*)&Als[row][cl * 16 + 8] = w1;
        }
    }
    // ---- GEMM phase ----
    f32x4 acc[2][4];
#pragma unroll
    for (int mi = 0; mi < 2; mi++)
#pragma unroll
        for (int ni = 0; ni < 4; ni++)
            acc[mi][ni] = f32x4{0.f, 0.f, 0.f, 0.f};
    auto stageW = [&](short (*Wsb)[64], int k0) {
#pragma unroll
        for (int r = 0; r < 4; r++)
            gl16(&W[(size_t)(o0 + r * 32 + w * 8 + srow) * CCH + k0 + sg * 8],
                 &Wsb[r * 32 + w * 8][0]);
    };
    auto compute = [&](int k0, short (*Wsb)[64]) {
#pragma unroll
        for (int half = 0; half < 2; half++) {
            int cg = (half << 2) | fq;
            bf16x8 af[2], wf[4];
#pragma unroll
            for (int mi = 0; mi < 2; mi++)
                af[mi] = *(const bf16x8*)&Als[wm + mi * 16 + fr][k0 + cg * 8];
#pragma unroll
            for (int ni = 0; ni < 4; ni++) {
                int row = wn + ni * 16 + fr;
                wf[ni] = *(const bf16x8*)&Wsb[row][(cg ^ (row & 7)) * 8];
            }
#pragma unroll
            for (int mi = 0; mi < 2; mi++)
#pragma unroll
                for (int ni = 0; ni < 4; ni++)
                    acc[mi][ni] = __builtin_amdgcn_mfma_f32_16x16x32_bf16(
                        af[mi], wf[ni], acc[mi][ni], 0, 0, 0);
        }
    };
    stageW(Ws0, 0);
    __syncthreads();
    stageW(Ws1, 64);
    compute(0, Ws0);
    __syncthreads();
    stageW(Ws0, 128);
    compute(64, Ws1);
    __syncthreads();
    stageW(Ws1, 192);
    compute(128, Ws0);
    __syncthreads();
    compute(192, Ws1);
#pragma unroll
    for (int mi = 0; mi < 2; mi++)
#pragma unroll
        for (int ni = 0; ni < 4; ni++)
#pragma unroll
            for (int r = 0; r < 4; r++) {
                int m = m0 + wm + mi * 16 + fq * 4 + r;
                int o = o0 + wn + ni * 16 + fr;
                outp[(size_t)m * HIDN + o] = f2bf(acc[mi][ni][r] + bias[o]);
            }
}

// ---------------- MFMA flash attention: 128 q rows/block, pi-permuted P (b64 stores) ----------------
__global__ __launch_bounds__(256, 3) void attn_mfma(const short* __restrict__ qb,
                                                    const short* __restrict__ kvk,
                                                    const short* __restrict__ vt,
                                                    short* __restrict__ o) {
    int blk = blockIdx.x;
    int qt = blk & 31; int hh = (blk >> 5) & 7; int b = blk >> 8;
    int t = threadIdx.x; int w = t >> 6; int lane = t & 63;
    int fr = lane & 15, fq = lane >> 4;
    __shared__ short Ks0[128][32], Ks1[128][32];   // 8 KB each
    __shared__ short Vt0[64][64],  Vt1[64][64];    // 8 KB each (permuted kv positions)
    __shared__ short Ps[4][2][16][64];             // 16 KB, per-wave x q-frag, permuted
    int n0 = qt * 128 + w * 16;
    bf16x8 qa[2];
#pragma unroll
    for (int mi = 0; mi < 2; mi++)
        qa[mi] = *(const bf16x8*)&qb[((size_t)(b * NN) + n0 + mi * 64 + fr) * CCH + hh * HD + fq * 8];
    f32x4 oacc[2][2];
    float lst[2][4];
#pragma unroll
    for (int mi = 0; mi < 2; mi++) {
#pragma unroll
        for (int nd = 0; nd < 2; nd++) oacc[mi][nd] = f32x4{0.f, 0.f, 0.f, 0.f};
#pragma unroll
        for (int r = 0; r < 4; r++) lst[mi][r] = 0.f;
    }

    int srowK = lane >> 2;                    // 0..15 (64B rows)
    int sgK   = (lane & 3) ^ (srowK & 3);
    int srowV = lane >> 3;                    // 0..7 (128B rows)
    int sgV   = (lane & 7) ^ srowV;

    auto stageKV = [&](short (*Ksb)[32], short (*Vtb)[64], int y0) {
#pragma unroll
        for (int r2 = 0; r2 < 2; r2++) {
            int rowK = r2 * 64 + w * 16 + srowK;
            gl16(&kvk[((size_t)(b * NKV) + y0 + rowK) * 256 + hh * HD + sgK * 8],
                 &Ksb[r2 * 64 + w * 16][0]);
        }
#pragma unroll
        for (int r3 = 0; r3 < 2; r3++) {
            int d = w * 8 + srowV;
            gl16(&vt[((size_t)((b * NH + hh) * HD) + d) * NKV + y0 + r3 * 64 + sgV * 8],
                 &Vtb[r3 * 32 + w * 8][0]);
        }
    };
    auto tile = [&](short (*Ksb)[32], short (*Vtb)[64]) {
#pragma unroll
        for (int h2 = 0; h2 < 2; h2++) {
#pragma unroll
            for (int mi = 0; mi < 2; mi++) {
                f32x4 s[4];
                __builtin_amdgcn_s_setprio(1);
#pragma unroll
                for (int ni = 0; ni < 4; ni++) {
                    int rowk = h2 * 64 + ni * 16 + fr;
                    bf16x8 kb = *(const bf16x8*)&Ksb[rowk][(fq ^ (fr & 3)) * 8];
                    s[ni] = __builtin_amdgcn_mfma_f32_16x16x32_bf16(
                        qa[mi], kb, f32x4{0.f, 0.f, 0.f, 0.f}, 0, 0, 0);
                }
                __builtin_amdgcn_s_setprio(0);
                // P: exp, pack 4 bf16, single b64 store at permuted position
#pragma unroll
                for (int r = 0; r < 4; r++) {
                    int row = fq * 4 + r;
                    float p0 = __expf(fminf(s[0][r], 30.f));
                    float p1 = __expf(fminf(s[1][r], 30.f));
                    float p2 = __expf(fminf(s[2][r], 30.f));
                    float p3 = __expf(fminf(s[3][r], 30.f));
                    lst[mi][r] += (p0 + p1) + (p2 + p3);
                    unsigned int w0 = cvtpk_bf16(p0, p1);
                    unsigned int w1 = cvtpk_bf16(p2, p3);
                    int gp = (fr >> 1) ^ (row & 7);     // 16B-group swizzle
                    *(uint2*)&Ps[w][mi][row][gp * 8 + (fr & 1) * 4] = make_uint2(w0, w1);
                }
                __builtin_amdgcn_s_setprio(1);
#pragma unroll
                for (int ks = 0; ks < 2; ks++) {
                    int gk = ks * 4 + fq;               // slot group 0..7
                    bf16x8 pa = *(const bf16x8*)&Ps[w][mi][fr][(gk ^ (fr & 7)) * 8];
#pragma unroll
                    for (int nd = 0; nd < 2; nd++) {
                        int rowv = nd * 16 + fr;
                        bf16x8 vb = *(const bf16x8*)&Vtb[h2 * 32 + rowv][(gk ^ (rowv & 7)) * 8];
                        oacc[mi][nd] = __builtin_amdgcn_mfma_f32_16x16x32_bf16(
                            pa, vb, oacc[mi][nd], 0, 0, 0);
                    }
                }
                __builtin_amdgcn_s_setprio(0);
            }
        }
    };

    stageKV(Ks0, Vt0, 0);
    __syncthreads();
    for (int y0 = 0; y0 < NKV; y0 += 256) {
        if (y0 + 128 < NKV) stageKV(Ks1, Vt1, y0 + 128);   // issue early
        tile(Ks0, Vt0);
        __syncthreads();                                   // wait late
        if (y0 + 256 < NKV) stageKV(Ks0, Vt0, y0 + 256);
        tile(Ks1, Vt1);
        __syncthreads();
    }
#pragma unroll
    for (int mi = 0; mi < 2; mi++)
#pragma unroll
        for (int r = 0; r < 4; r++) {
            float ls = lst[mi][r];
#pragma unroll
            for (int off = 1; off < 16; off <<= 1)
                ls += __shfl_xor(ls, off);
            float inv = 1.f / ls;
            int row = n0 + mi * 64 + fq * 4 + r;
#pragma unroll
            for (int nd = 0; nd < 2; nd++)
                o[((size_t)(b * NN) + row) * CCH + hh * HD + nd * 16 + fr] =
                    f2bf(oacc[mi][nd][r] * inv);
        }
}

// ---------------- depthwise 3x3 + bias + tanh-GELU, bf16 in/out ----------------
__global__ __launch_bounds__(256, 2) void dwconv_gelu(const short* __restrict__ xf,
                                                      const float* __restrict__ pe_w,
                                                      const float* __restrict__ pe_b,
                                                      short* __restrict__ out) {
    int blk = blockIdx.x;
    int cg = blk & 15, sp = (blk >> 4) & 15, b = blk >> 8;
    int r0 = (sp >> 2) * 16, c0 = (sp & 3) * 16;
    int ch0 = cg * 64;
    int t = threadIdx.x;
    __shared__ short tile[18][18][64];
    for (int idx = t; idx < 18 * 18 * 8; idx += 256) {
        int pix = idx >> 3, part = idx & 7;
        int row = pix / 18, col = pix - row * 18;
        int gr = r0 + row - 1, gc = c0 + col - 1;
        bf16x8 v = {0, 0, 0, 0, 0, 0, 0, 0};
        if (gr >= 0 && gr < 64 && gc >= 0 && gc < 64)
            v = *(const bf16x8*)&xf[((size_t)(b * NN) + gr * GW + gc) * HIDN + ch0 + part * 8];
        *(bf16x8*)&tile[row][col][part * 8] = v;
    }
    __syncthreads();
    int cl = t & 63, sg = t >> 6;
    int ch = ch0 + cl;
    float wv[9];
#pragma unroll
    for (int k = 0; k < 9; k++) wv[k] = pe_w[ch * 9 + k];
    float bias = pe_b[ch];
#pragma unroll
    for (int q = 0; q < 4; q++) {
        int lr = sg * 4 + q;
        float cA[3], cB[3], cC[3];
#pragma unroll
        for (int ki = 0; ki < 3; ki++) {
            cA[ki] = bf2f(tile[lr + ki][0][cl]);
            cB[ki] = bf2f(tile[lr + ki][1][cl]);
        }
        for (int cc = 0; cc < 16; cc++) {
#pragma unroll
            for (int ki = 0; ki < 3; ki++) cC[ki] = bf2f(tile[lr + ki][cc + 2][cl]);
            float acc = bias;
#pragma unroll
            for (int ki = 0; ki < 3; ki++)
                acc += cA[ki] * wv[ki * 3] + cB[ki] * wv[ki * 3 + 1] + cC[ki] * wv[ki * 3 + 2];
            float z = 0.7978845608f * (acc + 0.044715f * acc * acc * acc);
            float e = __expf(-2.f * fabsf(z));
            float th = (1.f - e) / (1.f + e);
            th = (z < 0.f) ? -th : th;
            float gg = 0.5f * acc * (1.f + th);
            out[((size_t)(b * NN) + (r0 + lr) * GW + c0 + cc) * HIDN + ch] = f2bf(gg);
#pragma unroll
            for (int ki = 0; ki < 3; ki++) { cA[ki] = cB[ki]; cB[ki] = cC[ki]; }
        }
    }
}

extern "C" void kernel_launch(void* const* d_in, const int* in_sizes, int n_in,
                              void* d_out, int out_size, void* d_ws, size_t ws_size,
                              hipStream_t stream) {
    const float* x      = (const float*)d_in[0];
    const float* ln1_g  = (const float*)d_in[3];
    const float* ln1_b  = (const float*)d_in[4];
    const float* q_w    = (const float*)d_in[5];
    const float* kv_w   = (const float*)d_in[6];
    const float* sr_w   = (const float*)d_in[7];
    const float* sr_b   = (const float*)d_in[8];
    const float* srn_g  = (const float*)d_in[9];
    const float* srn_b  = (const float*)d_in[10];
    const float* proj_w = (const float*)d_in[11];
    const float* proj_b = (const float*)d_in[12];
    const float* ln2_g  = (const float*)d_in[13];
    const float* ln2_b  = (const float*)d_in[14];
    const float* fc1_w  = (const float*)d_in[15];
    const float* fc1_b  = (const float*)d_in[16];
    const float* pe_w   = (const float*)d_in[17];
    const float* pe_b   = (const float*)d_in[18];
    const float* fc2_w  = (const float*)d_in[19];
    const float* fc2_b  = (const float*)d_in[20];
    float* out = (float*)d_out;

    // workspace carve (bytes)
    char* base = (char*)d_ws;
    short* xn    = (short*)(base);                   // [0,4M)   xn bf16 (LN1)
    short* qb    = (short*)(base + (4ull  << 20));   // [4,8)    q bf16 (pre-scaled)
    float* srtmp = (float*)(base + (12ull << 20));   // [12,14)  sr conv out f32 [2048][256]
    short* kvk   = (short*)(base + (15ull << 20));   // [15,16)  k bf16 [2048][256]
    short* vtb   = (short*)(base + (17ull << 20));   // [17,18)  V^T bf16 [512][1024] (permuted)
    short* obf   = (short*)(base + (18ull << 20));   // [18,22)  attn out bf16
    short* x1    = (short*)(base + (22ull << 20));   // [22,26)  x1 bf16
    short* xf1   = (short*)(base + (30ull << 20));   // [30,46)  fc1 out bf16 [8192][1024]
    short* xf2g  = (short*)(base + (46ull << 20));   // [46,62)  gelu(dwconv) bf16
    short* qwb   = (short*)(base + (62ull << 20));   // weights bf16
    short* kvwb  = qwb  + 65536;
    short* pjwb  = kvwb + 131072;
    short* f1wb  = pjwb + 65536;
    short* f2wb  = f1wb + 262144;
    short* srwb  = f2wb + 262144;

    // 0. weights -> bf16 (sr reordered) + LN1, one launch
    prep_kernel<<<4096 + BB * NN, 256, 0, stream>>>(q_w, kv_w, proj_w, fc1_w, fc2_w, sr_w,
                                                    qwb, kvwb, pjwb, f1wb, f2wb, srwb,
                                                    x, ln1_g, ln1_b, xn);
    // 2+3. q-GEMM and sr-GEMM merged
    qsr_gemm<<<768, 256, 0, stream>>>(xn, qwb, qb, srwb, sr_b, srtmp);
    // 4. kv = LN(srtmp) . kv_w^T -> kvk + vtb   (LN fused)
    {
        dim3 g(512 / 64, (BB * NKV) / 64);
        kvln_gemm<<<g, 256, 0, stream>>>(srtmp, srn_g, srn_b, kvwb, kvk, vtb);
    }
    // 5. attention -> obf (128 q rows/block)
    attn_mfma<<<BB * NH * (NN / 128), 256, 0, stream>>>(qb, kvk, vtb, obf);
    // 6. x1 = x + obf . proj_w^T + proj_b  (bf16 out)
    {
        dim3 g(CCH / 64, (BB * NN) / 64);
        gemm64<true, 1><<<g, 256, 0, stream>>>(obf, pjwb, proj_b, x, x1, BB * NN, CCH, CCH);
    }
    // 8. xf1 = LN2(x1) . fc1_w^T + fc1_b  (LN fused, 64x128 tile)
    {
        dim3 g(HIDN / 128, (BB * NN) / 64);
        fc1ln_gemm<<<g, 256, 0, stream>>>(x1, ln2_g, ln2_b, f1wb, fc1_b, xf1);
    }
    // 9. xf2g = gelu(dwconv3x3(xf1) + pe_b)
    dwconv_gelu<<<BB * 256, 256, 0, stream>>>(xf1, pe_w, pe_b, xf2g);
    // 10. out = x1 + xf2g . fc2_w^T + fc2_b  (f32)
    {
        dim3 g(CCH / 64, (BB * NN) / 64);
        gemm64<false, 2><<<g, 256, 0, stream>>>(xf2g, f2wb, fc2_b, x1, out, BB * NN, CCH, HIDN);
    }
}

// Round 15
// 115.757 us; speedup vs baseline: 1.0476x; 1.0476x over previous
//
#include <hip/hip_runtime.h>
#include <math.h>

// problem constants
constexpr int BB   = 2;
constexpr int NN   = 4096;
constexpr int CCH  = 256;   // channels
constexpr int NH   = 8;     // heads
constexpr int HD   = 32;    // head dim
constexpr int GW   = 64;    // spatial h = w
constexpr int NKV  = 1024;  // (64/2)*(64/2)
constexpr int HIDN = 1024;
constexpr float EPSF = 1e-5f;

typedef short  bf16x8 __attribute__((ext_vector_type(8)));
typedef short  bf16x4 __attribute__((ext_vector_type(4)));
typedef float  f32x4  __attribute__((ext_vector_type(4)));

__device__ __forceinline__ short f2bf(float f) {
    unsigned int u = __float_as_uint(f);
    unsigned int r = (u + 0x7FFFu + ((u >> 16) & 1u)) >> 16;   // RNE
    return (short)r;
}
__device__ __forceinline__ float bf2f(short s) {
    return __uint_as_float(((unsigned int)(unsigned short)s) << 16);
}
// packed f32x2 -> bf16x2 (RNE), src0 -> low half
__device__ __forceinline__ unsigned int cvtpk_bf16(float a, float b) {
    unsigned int r;
    asm("v_cvt_pk_bf16_f32 %0, %1, %2" : "=v"(r) : "v"(a), "v"(b));
    return r;
}
// async global->LDS, 16B per lane; lds base must be wave-uniform (HW adds lane*16)
__device__ __forceinline__ void gl16(const void* g, void* l) {
    __builtin_amdgcn_global_load_lds(
        (const __attribute__((address_space(1))) void*)g,
        (__attribute__((address_space(3))) void*)l, 16, 0, 0);
}

// ---------------- prep: weight cvt (blocks 0..4095) + LN1 (blocks 4096..12287) ----------------
// sr_w reordered: srwb[o][q*256+c] = sr_w[o][c*4+q]  (K-dim quad-major)
__global__ __launch_bounds__(256) void prep_kernel(const float* __restrict__ q_w,
                                                   const float* __restrict__ kv_w,
                                                   const float* __restrict__ proj_w,
                                                   const float* __restrict__ fc1_w,
                                                   const float* __restrict__ fc2_w,
                                                   const float* __restrict__ sr_w,
                                                   short* qwb, short* kvwb, short* pjwb,
                                                   short* f1wb, short* f2wb, short* srwb,
                                                   const float* __restrict__ x,
                                                   const float* __restrict__ ln1_g,
                                                   const float* __restrict__ ln1_b,
                                                   short* __restrict__ xn) {
    __shared__ float pa[4], pb[4];
    int t = threadIdx.x;
    if (blockIdx.x < 4096) {
        int i = blockIdx.x * 256 + t;
        if (i < 65536) { qwb[i] = f2bf(q_w[i] * 0.17677669529663687f); return; }
        i -= 65536;
        if (i < 131072) { kvwb[i] = f2bf(kv_w[i]); return; }
        i -= 131072;
        if (i < 65536) { pjwb[i] = f2bf(proj_w[i]); return; }
        i -= 65536;
        if (i < 262144) { f1wb[i] = f2bf(fc1_w[i]); return; }
        i -= 262144;
        if (i < 262144) { f2wb[i] = f2bf(fc2_w[i]); return; }
        i -= 262144;
        {
            int o = i >> 10, rem = i & 1023, c = rem >> 2, q = rem & 3;
            srwb[o * 1024 + q * 256 + c] = f2bf(sr_w[i]);
        }
        return;
    }
    int row = blockIdx.x - 4096;
    float v = x[row * CCH + t];
    float a = v, b = v * v;
#pragma unroll
    for (int off = 32; off > 0; off >>= 1) {
        a += __shfl_xor(a, off);
        b += __shfl_xor(b, off);
    }
    int w = t >> 6;
    if ((t & 63) == 0) { pa[w] = a; pb[w] = b; }
    __syncthreads();
    a = pa[0] + pa[1] + pa[2] + pa[3];
    b = pb[0] + pb[1] + pb[2] + pb[3];
    float mu = a * (1.0f / CCH);
    float var = b * (1.0f / CCH) - mu * mu;
    float rs = rsqrtf(var + EPSF);
    xn[row * CCH + t] = f2bf((v - mu) * rs * ln1_g[t] + ln1_b[t]);
}

// ---------------- wave-per-row LayerNorm (C=256): 4 rows/block, no barriers ----------------
template <bool INBF>
__global__ __launch_bounds__(256) void ln_wave(const void* __restrict__ in,
                                               const float* __restrict__ g,
                                               const float* __restrict__ bta,
                                               short* __restrict__ out) {
    int t = threadIdx.x;
    int w = t >> 6, lane = t & 63;
    int row = blockIdx.x * 4 + w;
    float v[4];
    if (INBF) {
        bf16x4 bv = *(const bf16x4*)&((const short*)in)[(size_t)row * CCH + lane * 4];
#pragma unroll
        for (int j = 0; j < 4; j++) v[j] = bf2f(bv[j]);
    } else {
        float4 fv = *(const float4*)&((const float*)in)[(size_t)row * CCH + lane * 4];
        v[0] = fv.x; v[1] = fv.y; v[2] = fv.z; v[3] = fv.w;
    }
    float a = v[0] + v[1] + v[2] + v[3];
    float b = v[0]*v[0] + v[1]*v[1] + v[2]*v[2] + v[3]*v[3];
#pragma unroll
    for (int off = 1; off < 64; off <<= 1) {
        a += __shfl_xor(a, off);
        b += __shfl_xor(b, off);
    }
    float mu = a * (1.0f / CCH);
    float var = b * (1.0f / CCH) - mu * mu;
    float rs = rsqrtf(var + EPSF);
    bf16x4 ov;
#pragma unroll
    for (int j = 0; j < 4; j++)
        ov[j] = f2bf((v[j] - mu) * rs * g[lane * 4 + j] + bta[lane * 4 + j]);
    *(bf16x4*)&out[(size_t)row * CCH + lane * 4] = ov;
}

// ---------------- gemm64 body (device fn): 64x64 tile, BK=64, 2-phase dbuf ----------------
template <bool OUTB, int RESMODE>
__device__ __forceinline__ void gemm64_body(const short* __restrict__ A,
                                            const short* __restrict__ W,
                                            const float* __restrict__ bias,
                                            const void* __restrict__ res,
                                            void* __restrict__ outp,
                                            int M, int O, int K, int bx, int by,
                                            short (*As0)[64], short (*Ws0)[64],
                                            short (*As1)[64], short (*Ws1)[64]) {
    int t = threadIdx.x;
    int m0 = by * 64, o0 = bx * 64;
    int w = t >> 6, lane = t & 63;
    int wm = (w >> 1) * 32, wn = (w & 1) * 32;
    int fr = lane & 15, fq = lane >> 4;
    int srow = lane >> 3;
    int sg   = (lane & 7) ^ srow;
    f32x4 acc[2][2];
#pragma unroll
    for (int mi = 0; mi < 2; mi++)
#pragma unroll
        for (int ni = 0; ni < 2; ni++)
            acc[mi][ni] = f32x4{0.f, 0.f, 0.f, 0.f};

    auto stage = [&](short (*Asb)[64], short (*Wsb)[64], int k0) {
#pragma unroll
        for (int r = 0; r < 2; r++) {
            int rowA = r * 32 + w * 8 + srow;
            gl16(&A[(size_t)(m0 + rowA) * K + k0 + sg * 8], &Asb[r * 32 + w * 8][0]);
            gl16(&W[(size_t)(o0 + rowA) * K + k0 + sg * 8], &Wsb[r * 32 + w * 8][0]);
        }
    };
    auto compute = [&](short (*Asb)[64], short (*Wsb)[64]) {
#pragma unroll
        for (int half = 0; half < 2; half++) {
            bf16x8 af[2], wf[2];
#pragma unroll
            for (int mi = 0; mi < 2; mi++) {
                int row = wm + mi * 16 + fr;
                af[mi] = *(const bf16x8*)&Asb[row][(((half << 2) | fq) ^ (row & 7)) * 8];
            }
#pragma unroll
            for (int ni = 0; ni < 2; ni++) {
                int row = wn + ni * 16 + fr;
                wf[ni] = *(const bf16x8*)&Wsb[row][(((half << 2) | fq) ^ (row & 7)) * 8];
            }
#pragma unroll
            for (int mi = 0; mi < 2; mi++)
#pragma unroll
                for (int ni = 0; ni < 2; ni++)
                    acc[mi][ni] = __builtin_amdgcn_mfma_f32_16x16x32_bf16(
                        af[mi], wf[ni], acc[mi][ni], 0, 0, 0);
        }
    };

    stage(As0, Ws0, 0);
    __syncthreads();
    for (int k0 = 0; k0 < K; k0 += 128) {
        if (k0 + 64 < K) stage(As1, Ws1, k0 + 64);
        compute(As0, Ws0);
        __syncthreads();
        if (k0 + 128 < K) stage(As0, Ws0, k0 + 128);
        if (k0 + 64 < K) compute(As1, Ws1);
        __syncthreads();
    }
#pragma unroll
    for (int mi = 0; mi < 2; mi++)
#pragma unroll
        for (int ni = 0; ni < 2; ni++)
#pragma unroll
            for (int r = 0; r < 4; r++) {
                int m = m0 + wm + mi * 16 + fq * 4 + r;
                int o = o0 + wn + ni * 16 + fr;
                float v = acc[mi][ni][r];
                if (bias) v += bias[o];
                if (RESMODE == 1) v += ((const float*)res)[(size_t)m * O + o];
                if (RESMODE == 2) v += bf2f(((const short*)res)[(size_t)m * O + o]);
                if (OUTB) ((short*)outp)[(size_t)m * O + o] = f2bf(v);
                else      ((float*)outp)[(size_t)m * O + o] = v;
            }
}

// standalone gemm64 kernel (proj, fc2)
template <bool OUTB, int RESMODE>
__global__ __launch_bounds__(256, 4) void gemm64(const short* __restrict__ A,
                                                 const short* __restrict__ W,
                                                 const float* __restrict__ bias,
                                                 const void* __restrict__ res,
                                                 void* __restrict__ outp,
                                                 int M, int O, int K) {
    __shared__ short As0[64][64], Ws0[64][64];
    __shared__ short As1[64][64], Ws1[64][64];
    gemm64_body<OUTB, RESMODE>(A, W, bias, res, outp, M, O, K,
                               blockIdx.x, blockIdx.y, As0, Ws0, As1, Ws1);
}

// ---------------- SR conv body: fused im2col gather (K reordered: k = q*256+c) ----------------
__device__ __forceinline__ void sr_body(const short* __restrict__ xn,
                                        const short* __restrict__ Wsr,
                                        const float* __restrict__ sr_b,
                                        float* __restrict__ srtmp, int bx, int by,
                                        short (*As0)[64], short (*As1)[64],
                                        short (*Ws0)[64], short (*Ws1)[64]) {
    int t = threadIdx.x;
    int m0 = by * 32, o0 = bx * 64;
    int w = t >> 6, lane = t & 63;
    int wm = (w >> 1) * 16, wn = (w & 1) * 32;
    int fr = lane & 15, fq = lane >> 4;
    int srow = lane >> 3;
    int sg   = (lane & 7) ^ srow;
    int arow = w * 8 + srow;
    int p = m0 + arow;
    int b = p >> 10, pp = p & 1023, ii = pp >> 5, jj = pp & 31;
    int nbase = ii * 128 + jj * 2;
    size_t xbase = (size_t)(b * NN) * CCH;
    f32x4 acc[2];
    acc[0] = f32x4{0.f, 0.f, 0.f, 0.f};
    acc[1] = f32x4{0.f, 0.f, 0.f, 0.f};

    auto stage = [&](short (*Asb)[64], short (*Wsb)[64], int k0) {
        int q = k0 >> 8, c0 = k0 & 255;
        int n = nbase + (q >> 1) * 64 + (q & 1);
        gl16(&xn[xbase + (size_t)n * CCH + c0 + sg * 8], &Asb[w * 8][0]);
#pragma unroll
        for (int r = 0; r < 2; r++)
            gl16(&Wsr[(size_t)(o0 + r * 32 + w * 8 + srow) * 1024 + k0 + sg * 8],
                 &Wsb[r * 32 + w * 8][0]);
    };
    auto compute = [&](short (*Asb)[64], short (*Wsb)[64]) {
#pragma unroll
        for (int half = 0; half < 2; half++) {
            int cg = (half << 2) | fq;
            int rowa = wm + fr;
            bf16x8 af = *(const bf16x8*)&Asb[rowa][(cg ^ (rowa & 7)) * 8];
            bf16x8 wf[2];
#pragma unroll
            for (int ni = 0; ni < 2; ni++) {
                int row = wn + ni * 16 + fr;
                wf[ni] = *(const bf16x8*)&Wsb[row][(cg ^ (row & 7)) * 8];
            }
#pragma unroll
            for (int ni = 0; ni < 2; ni++)
                acc[ni] = __builtin_amdgcn_mfma_f32_16x16x32_bf16(
                    af, wf[ni], acc[ni], 0, 0, 0);
        }
    };

    stage(As0, Ws0, 0);
    __syncthreads();
    for (int k0 = 0; k0 < 1024; k0 += 128) {
        if (k0 + 64 < 1024) stage(As1, Ws1, k0 + 64);
        compute(As0, Ws0);
        __syncthreads();
        if (k0 + 128 < 1024) stage(As0, Ws0, k0 + 128);
        compute(As1, Ws1);
        __syncthreads();
    }
#pragma unroll
    for (int ni = 0; ni < 2; ni++)
#pragma unroll
        for (int r = 0; r < 4; r++) {
            int m = m0 + wm + fq * 4 + r;
            int o = o0 + wn + ni * 16 + fr;
            srtmp[(size_t)m * CCH + o] = acc[ni][r] + sr_b[o];
        }
}

// ---------------- merged q-GEMM (blocks 0..511) + sr-GEMM (blocks 512..767) ----------------
__global__ __launch_bounds__(256, 4) void qsr_gemm(const short* __restrict__ xn,
                                                   const short* __restrict__ qwb,
                                                   short* __restrict__ qb,
                                                   const short* __restrict__ srwb,
                                                   const float* __restrict__ sr_b,
                                                   float* __restrict__ srtmp) {
    __shared__ short pool[16384];   // 32 KB
    int i = blockIdx.x;
    if (i < 512) {
        gemm64_body<true, 0>(xn, qwb, nullptr, nullptr, qb, BB * NN, CCH, CCH,
                             i & 3, i >> 2,
                             (short(*)[64])(pool),
                             (short(*)[64])(pool + 4096),
                             (short(*)[64])(pool + 8192),
                             (short(*)[64])(pool + 12288));
    } else {
        i -= 512;
        sr_body(xn, srwb, sr_b, srtmp, i & 3, i >> 2,
                (short(*)[64])(pool),
                (short(*)[64])(pool + 2048),
                (short(*)[64])(pool + 4096),
                (short(*)[64])(pool + 8192));
    }
}

// ---------------- fc1 GEMM, 128x128 tile, BK=64, dbuf ----------------
__global__ __launch_bounds__(256, 2) void gemm_fc1(const short* __restrict__ A,
                                                   const short* __restrict__ W,
                                                   const float* __restrict__ bias,
                                                   short* __restrict__ outp,
                                                   int M, int O, int K) {
    __shared__ short As0[128][64], Ws0[128][64];
    __shared__ short As1[128][64], Ws1[128][64];
    int t = threadIdx.x;
    int m0 = blockIdx.y * 128, o0 = blockIdx.x * 128;
    int w = t >> 6, lane = t & 63;
    int wm = (w >> 1) * 64, wn = (w & 1) * 64;
    int fr = lane & 15, fq = lane >> 4;
    int srow = lane >> 3;
    int sg   = (lane & 7) ^ srow;
    f32x4 acc[4][4];
#pragma unroll
    for (int mi = 0; mi < 4; mi++)
#pragma unroll
        for (int ni = 0; ni < 4; ni++)
            acc[mi][ni] = f32x4{0.f, 0.f, 0.f, 0.f};

    auto stage = [&](short (*Asb)[64], short (*Wsb)[64], int k0) {
#pragma unroll
        for (int r = 0; r < 4; r++) {
            int rowA = r * 32 + w * 8 + srow;
            gl16(&A[(size_t)(m0 + rowA) * K + k0 + sg * 8], &Asb[r * 32 + w * 8][0]);
            gl16(&W[(size_t)(o0 + rowA) * K + k0 + sg * 8], &Wsb[r * 32 + w * 8][0]);
        }
    };
    auto compute = [&](short (*Asb)[64], short (*Wsb)[64]) {
#pragma unroll
        for (int half = 0; half < 2; half++) {
            bf16x8 af[4], wf[4];
#pragma unroll
            for (int mi = 0; mi < 4; mi++) {
                int row = wm + mi * 16 + fr;
                af[mi] = *(const bf16x8*)&Asb[row][(((half << 2) | fq) ^ (row & 7)) * 8];
            }
#pragma unroll
            for (int ni = 0; ni < 4; ni++) {
                int row = wn + ni * 16 + fr;
                wf[ni] = *(const bf16x8*)&Wsb[row][(((half << 2) | fq) ^ (row & 7)) * 8];
            }
#pragma unroll
            for (int mi = 0; mi < 4; mi++)
#pragma unroll
                for (int ni = 0; ni < 4; ni++)
                    acc[mi][ni] = __builtin_amdgcn_mfma_f32_16x16x32_bf16(
                        af[mi], wf[ni], acc[mi][ni], 0, 0, 0);
        }
    };

    stage(As0, Ws0, 0);
    __syncthreads();
    for (int k0 = 0; k0 < K; k0 += 128) {
        if (k0 + 64 < K) stage(As1, Ws1, k0 + 64);
        compute(As0, Ws0);
        __syncthreads();
        if (k0 + 128 < K) stage(As0, Ws0, k0 + 128);
        if (k0 + 64 < K) compute(As1, Ws1);
        __syncthreads();
    }
#pragma unroll
    for (int mi = 0; mi < 4; mi++)
#pragma unroll
        for (int ni = 0; ni < 4; ni++)
#pragma unroll
            for (int r = 0; r < 4; r++) {
                int m = m0 + wm + mi * 16 + fq * 4 + r;
                int o = o0 + wn + ni * 16 + fr;
                outp[(size_t)m * O + o] = f2bf(acc[mi][ni][r] + bias[o]);
            }
}

// ---------------- kv GEMM with fused V-transpose epilogue ----------------
// o<256 -> kvk[m][o] bf16; o>=256 -> vt permuted: within each 64-kv block,
// kv y stored at s=(y&15)*4+(y>>4).
__global__ __launch_bounds__(256, 4) void kv_gemm(const short* __restrict__ A,
                                                  const short* __restrict__ W,
                                                  short* __restrict__ kvk,
                                                  short* __restrict__ vt) {
    __shared__ short As0[64][64], Ws0[64][64];
    __shared__ short As1[64][64], Ws1[64][64];
    int t = threadIdx.x;
    int m0 = blockIdx.y * 64, o0 = blockIdx.x * 64;
    int w = t >> 6, lane = t & 63;
    int wm = (w >> 1) * 32, wn = (w & 1) * 32;
    int fr = lane & 15, fq = lane >> 4;
    int srow = lane >> 3;
    int sg   = (lane & 7) ^ srow;
    f32x4 acc[2][2];
#pragma unroll
    for (int mi = 0; mi < 2; mi++)
#pragma unroll
        for (int ni = 0; ni < 2; ni++)
            acc[mi][ni] = f32x4{0.f, 0.f, 0.f, 0.f};

    auto stage = [&](short (*Asb)[64], short (*Wsb)[64], int k0) {
#pragma unroll
        for (int r = 0; r < 2; r++) {
            int rowA = r * 32 + w * 8 + srow;
            gl16(&A[(size_t)(m0 + rowA) * CCH + k0 + sg * 8], &Asb[r * 32 + w * 8][0]);
            gl16(&W[(size_t)(o0 + rowA) * CCH + k0 + sg * 8], &Wsb[r * 32 + w * 8][0]);
        }
    };
    auto compute = [&](short (*Asb)[64], short (*Wsb)[64]) {
#pragma unroll
        for (int half = 0; half < 2; half++) {
            bf16x8 af[2], wf[2];
#pragma unroll
            for (int mi = 0; mi < 2; mi++) {
                int row = wm + mi * 16 + fr;
                af[mi] = *(const bf16x8*)&Asb[row][(((half << 2) | fq) ^ (row & 7)) * 8];
            }
#pragma unroll
            for (int ni = 0; ni < 2; ni++) {
                int row = wn + ni * 16 + fr;
                wf[ni] = *(const bf16x8*)&Wsb[row][(((half << 2) | fq) ^ (row & 7)) * 8];
            }
#pragma unroll
            for (int mi = 0; mi < 2; mi++)
#pragma unroll
                for (int ni = 0; ni < 2; ni++)
                    acc[mi][ni] = __builtin_amdgcn_mfma_f32_16x16x32_bf16(
                        af[mi], wf[ni], acc[mi][ni], 0, 0, 0);
        }
    };

    stage(As0, Ws0, 0);
    __syncthreads();
    stage(As1, Ws1, 64);
    compute(As0, Ws0);
    __syncthreads();
    stage(As0, Ws0, 128);
    compute(As1, Ws1);
    __syncthreads();
    stage(As1, Ws1, 192);
    compute(As0, Ws0);
    __syncthreads();
    compute(As1, Ws1);

#pragma unroll
    for (int mi = 0; mi < 2; mi++)
#pragma unroll
        for (int ni = 0; ni < 2; ni++) {
            int o = o0 + wn + ni * 16 + fr;
            int mbase = m0 + wm + mi * 16 + fq * 4;
            if (o < 256) {
#pragma unroll
                for (int r = 0; r < 4; r++)
                    kvk[(size_t)(mbase + r) * 256 + o] = f2bf(acc[mi][ni][r]);
            } else {
                int h = (o - 256) >> 5, d = (o - 256) & 31;
                int b = mbase >> 10, y0 = mbase & 1023;
                size_t rowbase = ((size_t)((b * NH + h) * HD) + d) * NKV + (y0 >> 6) * 64;
                int y4 = y0 & 63;
#pragma unroll
                for (int r = 0; r < 4; r++) {
                    int y64 = y4 + r;
                    int s = (y64 & 15) * 4 + (y64 >> 4);
                    vt[rowbase + s] = f2bf(acc[mi][ni][r]);
                }
            }
        }
}

// ---------------- MFMA flash attention: 128 q rows/block, pi-permuted P (b64 stores) ----------------
__global__ __launch_bounds__(256, 3) void attn_mfma(const short* __restrict__ qb,
                                                    const short* __restrict__ kvk,
                                                    const short* __restrict__ vt,
                                                    short* __restrict__ o) {
    int blk = blockIdx.x;
    int qt = blk & 31; int hh = (blk >> 5) & 7; int b = blk >> 8;
    int t = threadIdx.x; int w = t >> 6; int lane = t & 63;
    int fr = lane & 15, fq = lane >> 4;
    __shared__ short Ks0[128][32], Ks1[128][32];   // 8 KB each
    __shared__ short Vt0[64][64],  Vt1[64][64];    // 8 KB each (permuted kv positions)
    __shared__ short Ps[4][2][16][64];             // 16 KB, per-wave x q-frag, permuted
    int n0 = qt * 128 + w * 16;
    bf16x8 qa[2];
#pragma unroll
    for (int mi = 0; mi < 2; mi++)
        qa[mi] = *(const bf16x8*)&qb[((size_t)(b * NN) + n0 + mi * 64 + fr) * CCH + hh * HD + fq * 8];
    f32x4 oacc[2][2];
    float lst[2][4];
#pragma unroll
    for (int mi = 0; mi < 2; mi++) {
#pragma unroll
        for (int nd = 0; nd < 2; nd++) oacc[mi][nd] = f32x4{0.f, 0.f, 0.f, 0.f};
#pragma unroll
        for (int r = 0; r < 4; r++) lst[mi][r] = 0.f;
    }

    int srowK = lane >> 2;                    // 0..15 (64B rows)
    int sgK   = (lane & 3) ^ (srowK & 3);
    int srowV = lane >> 3;                    // 0..7 (128B rows)
    int sgV   = (lane & 7) ^ srowV;

    auto stageKV = [&](short (*Ksb)[32], short (*Vtb)[64], int y0) {
#pragma unroll
        for (int r2 = 0; r2 < 2; r2++) {
            int rowK = r2 * 64 + w * 16 + srowK;
            gl16(&kvk[((size_t)(b * NKV) + y0 + rowK) * 256 + hh * HD + sgK * 8],
                 &Ksb[r2 * 64 + w * 16][0]);
        }
#pragma unroll
        for (int r3 = 0; r3 < 2; r3++) {
            int d = w * 8 + srowV;
            gl16(&vt[((size_t)((b * NH + hh) * HD) + d) * NKV + y0 + r3 * 64 + sgV * 8],
                 &Vtb[r3 * 32 + w * 8][0]);
        }
    };
    auto tile = [&](short (*Ksb)[32], short (*Vtb)[64]) {
#pragma unroll
        for (int h2 = 0; h2 < 2; h2++) {
#pragma unroll
            for (int mi = 0; mi < 2; mi++) {
                f32x4 s[4];
                __builtin_amdgcn_s_setprio(1);
#pragma unroll
                for (int ni = 0; ni < 4; ni++) {
                    int rowk = h2 * 64 + ni * 16 + fr;
                    bf16x8 kb = *(const bf16x8*)&Ksb[rowk][(fq ^ (fr & 3)) * 8];
                    s[ni] = __builtin_amdgcn_mfma_f32_16x16x32_bf16(
                        qa[mi], kb, f32x4{0.f, 0.f, 0.f, 0.f}, 0, 0, 0);
                }
                __builtin_amdgcn_s_setprio(0);
                // P: exp, pack 4 bf16, single b64 store at permuted position
#pragma unroll
                for (int r = 0; r < 4; r++) {
                    int row = fq * 4 + r;
                    float p0 = __expf(fminf(s[0][r], 30.f));
                    float p1 = __expf(fminf(s[1][r], 30.f));
                    float p2 = __expf(fminf(s[2][r], 30.f));
                    float p3 = __expf(fminf(s[3][r], 30.f));
                    lst[mi][r] += (p0 + p1) + (p2 + p3);
                    unsigned int w0 = cvtpk_bf16(p0, p1);
                    unsigned int w1 = cvtpk_bf16(p2, p3);
                    int gp = (fr >> 1) ^ (row & 7);     // 16B-group swizzle
                    *(uint2*)&Ps[w][mi][row][gp * 8 + (fr & 1) * 4] = make_uint2(w0, w1);
                }
                __builtin_amdgcn_s_setprio(1);
#pragma unroll
                for (int ks = 0; ks < 2; ks++) {
                    int gk = ks * 4 + fq;               // slot group 0..7
                    bf16x8 pa = *(const bf16x8*)&Ps[w][mi][fr][(gk ^ (fr & 7)) * 8];
#pragma unroll
                    for (int nd = 0; nd < 2; nd++) {
                        int rowv = nd * 16 + fr;
                        bf16x8 vb = *(const bf16x8*)&Vtb[h2 * 32 + rowv][(gk ^ (rowv & 7)) * 8];
                        oacc[mi][nd] = __builtin_amdgcn_mfma_f32_16x16x32_bf16(
                            pa, vb, oacc[mi][nd], 0, 0, 0);
                    }
                }
                __builtin_amdgcn_s_setprio(0);
            }
        }
    };

    stageKV(Ks0, Vt0, 0);
    __syncthreads();
    for (int y0 = 0; y0 < NKV; y0 += 256) {
        if (y0 + 128 < NKV) stageKV(Ks1, Vt1, y0 + 128);   // issue early
        tile(Ks0, Vt0);
        __syncthreads();                                   // wait late
        if (y0 + 256 < NKV) stageKV(Ks0, Vt0, y0 + 256);
        tile(Ks1, Vt1);
        __syncthreads();
    }
#pragma unroll
    for (int mi = 0; mi < 2; mi++)
#pragma unroll
        for (int r = 0; r < 4; r++) {
            float ls = lst[mi][r];
#pragma unroll
            for (int off = 1; off < 16; off <<= 1)
                ls += __shfl_xor(ls, off);
            float inv = 1.f / ls;
            int row = n0 + mi * 64 + fq * 4 + r;
#pragma unroll
            for (int nd = 0; nd < 2; nd++)
                o[((size_t)(b * NN) + row) * CCH + hh * HD + nd * 16 + fr] =
                    f2bf(oacc[mi][nd][r] * inv);
        }
}

// ---------------- depthwise 3x3 + bias + tanh-GELU, bf16 in/out ----------------
__global__ __launch_bounds__(256, 2) void dwconv_gelu(const short* __restrict__ xf,
                                                      const float* __restrict__ pe_w,
                                                      const float* __restrict__ pe_b,
                                                      short* __restrict__ out) {
    int blk = blockIdx.x;
    int cg = blk & 15, sp = (blk >> 4) & 15, b = blk >> 8;
    int r0 = (sp >> 2) * 16, c0 = (sp & 3) * 16;
    int ch0 = cg * 64;
    int t = threadIdx.x;
    __shared__ short tile[18][18][64];
    for (int idx = t; idx < 18 * 18 * 8; idx += 256) {
        int pix = idx >> 3, part = idx & 7;
        int row = pix / 18, col = pix - row * 18;
        int gr = r0 + row - 1, gc = c0 + col - 1;
        bf16x8 v = {0, 0, 0, 0, 0, 0, 0, 0};
        if (gr >= 0 && gr < 64 && gc >= 0 && gc < 64)
            v = *(const bf16x8*)&xf[((size_t)(b * NN) + gr * GW + gc) * HIDN + ch0 + part * 8];
        *(bf16x8*)&tile[row][col][part * 8] = v;
    }
    __syncthreads();
    int cl = t & 63, sg = t >> 6;
    int ch = ch0 + cl;
    float wv[9];
#pragma unroll
    for (int k = 0; k < 9; k++) wv[k] = pe_w[ch * 9 + k];
    float bias = pe_b[ch];
#pragma unroll
    for (int q = 0; q < 4; q++) {
        int lr = sg * 4 + q;
        float cA[3], cB[3], cC[3];
#pragma unroll
        for (int ki = 0; ki < 3; ki++) {
            cA[ki] = bf2f(tile[lr + ki][0][cl]);
            cB[ki] = bf2f(tile[lr + ki][1][cl]);
        }
        for (int cc = 0; cc < 16; cc++) {
#pragma unroll
            for (int ki = 0; ki < 3; ki++) cC[ki] = bf2f(tile[lr + ki][cc + 2][cl]);
            float acc = bias;
#pragma unroll
            for (int ki = 0; ki < 3; ki++)
                acc += cA[ki] * wv[ki * 3] + cB[ki] * wv[ki * 3 + 1] + cC[ki] * wv[ki * 3 + 2];
            float z = 0.7978845608f * (acc + 0.044715f * acc * acc * acc);
            float e = __expf(-2.f * fabsf(z));
            float th = (1.f - e) / (1.f + e);
            th = (z < 0.f) ? -th : th;
            float gg = 0.5f * acc * (1.f + th);
            out[((size_t)(b * NN) + (r0 + lr) * GW + c0 + cc) * HIDN + ch] = f2bf(gg);
#pragma unroll
            for (int ki = 0; ki < 3; ki++) { cA[ki] = cB[ki]; cB[ki] = cC[ki]; }
        }
    }
}

extern "C" void kernel_launch(void* const* d_in, const int* in_sizes, int n_in,
                              void* d_out, int out_size, void* d_ws, size_t ws_size,
                              hipStream_t stream) {
    const float* x      = (const float*)d_in[0];
    const float* ln1_g  = (const float*)d_in[3];
    const float* ln1_b  = (const float*)d_in[4];
    const float* q_w    = (const float*)d_in[5];
    const float* kv_w   = (const float*)d_in[6];
    const float* sr_w   = (const float*)d_in[7];
    const float* sr_b   = (const float*)d_in[8];
    const float* srn_g  = (const float*)d_in[9];
    const float* srn_b  = (const float*)d_in[10];
    const float* proj_w = (const float*)d_in[11];
    const float* proj_b = (const float*)d_in[12];
    const float* ln2_g  = (const float*)d_in[13];
    const float* ln2_b  = (const float*)d_in[14];
    const float* fc1_w  = (const float*)d_in[15];
    const float* fc1_b  = (const float*)d_in[16];
    const float* pe_w   = (const float*)d_in[17];
    const float* pe_b   = (const float*)d_in[18];
    const float* fc2_w  = (const float*)d_in[19];
    const float* fc2_b  = (const float*)d_in[20];
    float* out = (float*)d_out;

    // workspace carve (bytes)
    char* base = (char*)d_ws;
    short* xn    = (short*)(base);                   // [0,4M)   xn / xn2 bf16
    short* qb    = (short*)(base + (4ull  << 20));   // [4,8)    q bf16 (pre-scaled)
    float* srtmp = (float*)(base + (12ull << 20));   // [12,14)  sr conv out f32 [2048][256]
    short* xkvn  = (short*)(base + (14ull << 20));   // [14,15)  x_kvn bf16
    short* kvk   = (short*)(base + (15ull << 20));   // [15,16)  k bf16 [2048][256]
    short* vtb   = (short*)(base + (17ull << 20));   // [17,18)  V^T bf16 [512][1024] (permuted)
    short* obf   = (short*)(base + (18ull << 20));   // [18,22)  attn out bf16
    short* x1    = (short*)(base + (22ull << 20));   // [22,26)  x1 bf16
    short* xf1   = (short*)(base + (30ull << 20));   // [30,46)  fc1 out bf16 [8192][1024]
    short* xf2g  = (short*)(base + (46ull << 20));   // [46,62)  gelu(dwconv) bf16
    short* qwb   = (short*)(base + (62ull << 20));   // weights bf16
    short* kvwb  = qwb  + 65536;
    short* pjwb  = kvwb + 131072;
    short* f1wb  = pjwb + 65536;
    short* f2wb  = f1wb + 262144;
    short* srwb  = f2wb + 262144;

    // 0. weights -> bf16 (sr reordered) + LN1, one launch
    prep_kernel<<<4096 + BB * NN, 256, 0, stream>>>(q_w, kv_w, proj_w, fc1_w, fc2_w, sr_w,
                                                    qwb, kvwb, pjwb, f1wb, f2wb, srwb,
                                                    x, ln1_g, ln1_b, xn);
    // 2+3. q-GEMM and sr-GEMM merged
    qsr_gemm<<<768, 256, 0, stream>>>(xn, qwb, qb, srwb, sr_b, srtmp);
    // 3c. x_kvn = LN(srtmp)
    ln_wave<false><<<BB * NKV / 4, 256, 0, stream>>>(srtmp, srn_g, srn_b, xkvn);
    // 4. kv = x_kvn . kv_w^T -> kvk (k half) + vtb (v half, transposed+permuted)
    {
        dim3 g(512 / 64, (BB * NKV) / 64);
        kv_gemm<<<g, 256, 0, stream>>>(xkvn, kvwb, kvk, vtb);
    }
    // 5. attention -> obf (128 q rows/block)
    attn_mfma<<<BB * NH * (NN / 128), 256, 0, stream>>>(qb, kvk, vtb, obf);
    // 6. x1 = x + obf . proj_w^T + proj_b  (bf16 out)
    {
        dim3 g(CCH / 64, (BB * NN) / 64);
        gemm64<true, 1><<<g, 256, 0, stream>>>(obf, pjwb, proj_b, x, x1, BB * NN, CCH, CCH);
    }
    // 7. xn2 = LN2(x1) (bf16 in, reuse xn)
    ln_wave<true><<<BB * NN / 4, 256, 0, stream>>>(x1, ln2_g, ln2_b, xn);
    // 8. xf1 = xn2 . fc1_w^T + fc1_b  (bf16 out, 128x128 tile)
    {
        dim3 g(HIDN / 128, (BB * NN) / 128);
        gemm_fc1<<<g, 256, 0, stream>>>(xn, f1wb, fc1_b, xf1, BB * NN, HIDN, CCH);
    }
    // 9. xf2g = gelu(dwconv3x3(xf1) + pe_b)
    dwconv_gelu<<<BB * 256, 256, 0, stream>>>(xf1, pe_w, pe_b, xf2g);
    // 10. out = x1 + xf2g . fc2_w^T + fc2_b  (f32)
    {
        dim3 g(CCH / 64, (BB * NN) / 64);
        gemm64<false, 2><<<g, 256, 0, stream>>>(xf2g, f2wb, fc2_b, x1, out, BB * NN, CCH, HIDN);
    }
}

// Round 16
// 113.195 us; speedup vs baseline: 1.0713x; 1.0226x over previous
//
#include <hip/hip_runtime.h>
#include <math.h>

// problem constants
constexpr int BB   = 2;
constexpr int NN   = 4096;
constexpr int CCH  = 256;   // channels
constexpr int NH   = 8;     // heads
constexpr int HD   = 32;    // head dim
constexpr int GW   = 64;    // spatial h = w
constexpr int NKV  = 1024;  // (64/2)*(64/2)
constexpr int HIDN = 1024;
constexpr float EPSF = 1e-5f;

typedef short  bf16x8 __attribute__((ext_vector_type(8)));
typedef short  bf16x4 __attribute__((ext_vector_type(4)));
typedef float  f32x4  __attribute__((ext_vector_type(4)));

__device__ __forceinline__ short f2bf(float f) {
    unsigned int u = __float_as_uint(f);
    unsigned int r = (u + 0x7FFFu + ((u >> 16) & 1u)) >> 16;   // RNE
    return (short)r;
}
__device__ __forceinline__ float bf2f(short s) {
    return __uint_as_float(((unsigned int)(unsigned short)s) << 16);
}
// packed f32x2 -> bf16x2 (RNE), src0 -> low half
__device__ __forceinline__ unsigned int cvtpk_bf16(float a, float b) {
    unsigned int r;
    asm("v_cvt_pk_bf16_f32 %0, %1, %2" : "=v"(r) : "v"(a), "v"(b));
    return r;
}
// async global->LDS, 16B per lane; lds base must be wave-uniform (HW adds lane*16)
__device__ __forceinline__ void gl16(const void* g, void* l) {
    __builtin_amdgcn_global_load_lds(
        (const __attribute__((address_space(1))) void*)g,
        (__attribute__((address_space(3))) void*)l, 16, 0, 0);
}

// ---------------- prep: weight cvt (blocks 0..4095) + LN1 (blocks 4096..12287) ----------------
// sr_w reordered: srwb[o][q*256+c] = sr_w[o][c*4+q]  (K-dim quad-major)
__global__ __launch_bounds__(256) void prep_kernel(const float* __restrict__ q_w,
                                                   const float* __restrict__ kv_w,
                                                   const float* __restrict__ proj_w,
                                                   const float* __restrict__ fc1_w,
                                                   const float* __restrict__ fc2_w,
                                                   const float* __restrict__ sr_w,
                                                   short* qwb, short* kvwb, short* pjwb,
                                                   short* f1wb, short* f2wb, short* srwb,
                                                   const float* __restrict__ x,
                                                   const float* __restrict__ ln1_g,
                                                   const float* __restrict__ ln1_b,
                                                   short* __restrict__ xn) {
    __shared__ float pa[4], pb[4];
    int t = threadIdx.x;
    if (blockIdx.x < 4096) {
        int i = blockIdx.x * 256 + t;
        if (i < 65536) { qwb[i] = f2bf(q_w[i] * 0.17677669529663687f); return; }
        i -= 65536;
        if (i < 131072) { kvwb[i] = f2bf(kv_w[i]); return; }
        i -= 131072;
        if (i < 65536) { pjwb[i] = f2bf(proj_w[i]); return; }
        i -= 65536;
        if (i < 262144) { f1wb[i] = f2bf(fc1_w[i]); return; }
        i -= 262144;
        if (i < 262144) { f2wb[i] = f2bf(fc2_w[i]); return; }
        i -= 262144;
        {
            int o = i >> 10, rem = i & 1023, c = rem >> 2, q = rem & 3;
            srwb[o * 1024 + q * 256 + c] = f2bf(sr_w[i]);
        }
        return;
    }
    int row = blockIdx.x - 4096;
    float v = x[row * CCH + t];
    float a = v, b = v * v;
#pragma unroll
    for (int off = 32; off > 0; off >>= 1) {
        a += __shfl_xor(a, off);
        b += __shfl_xor(b, off);
    }
    int w = t >> 6;
    if ((t & 63) == 0) { pa[w] = a; pb[w] = b; }
    __syncthreads();
    a = pa[0] + pa[1] + pa[2] + pa[3];
    b = pb[0] + pb[1] + pb[2] + pb[3];
    float mu = a * (1.0f / CCH);
    float var = b * (1.0f / CCH) - mu * mu;
    float rs = rsqrtf(var + EPSF);
    xn[row * CCH + t] = f2bf((v - mu) * rs * ln1_g[t] + ln1_b[t]);
}

// ---------------- wave-per-row LayerNorm (C=256): 4 rows/block, no barriers ----------------
template <bool INBF>
__global__ __launch_bounds__(256) void ln_wave(const void* __restrict__ in,
                                               const float* __restrict__ g,
                                               const float* __restrict__ bta,
                                               short* __restrict__ out) {
    int t = threadIdx.x;
    int w = t >> 6, lane = t & 63;
    int row = blockIdx.x * 4 + w;
    float v[4];
    if (INBF) {
        bf16x4 bv = *(const bf16x4*)&((const short*)in)[(size_t)row * CCH + lane * 4];
#pragma unroll
        for (int j = 0; j < 4; j++) v[j] = bf2f(bv[j]);
    } else {
        float4 fv = *(const float4*)&((const float*)in)[(size_t)row * CCH + lane * 4];
        v[0] = fv.x; v[1] = fv.y; v[2] = fv.z; v[3] = fv.w;
    }
    float a = v[0] + v[1] + v[2] + v[3];
    float b = v[0]*v[0] + v[1]*v[1] + v[2]*v[2] + v[3]*v[3];
#pragma unroll
    for (int off = 1; off < 64; off <<= 1) {
        a += __shfl_xor(a, off);
        b += __shfl_xor(b, off);
    }
    float mu = a * (1.0f / CCH);
    float var = b * (1.0f / CCH) - mu * mu;
    float rs = rsqrtf(var + EPSF);
    bf16x4 ov;
#pragma unroll
    for (int j = 0; j < 4; j++)
        ov[j] = f2bf((v[j] - mu) * rs * g[lane * 4 + j] + bta[lane * 4 + j]);
    *(bf16x4*)&out[(size_t)row * CCH + lane * 4] = ov;
}

// ---------------- gemm64 body (device fn): 64x64 tile, BK=64, 2-phase dbuf ----------------
template <bool OUTB, int RESMODE>
__device__ __forceinline__ void gemm64_body(const short* __restrict__ A,
                                            const short* __restrict__ W,
                                            const float* __restrict__ bias,
                                            const void* __restrict__ res,
                                            void* __restrict__ outp,
                                            int M, int O, int K, int bx, int by,
                                            short (*As0)[64], short (*Ws0)[64],
                                            short (*As1)[64], short (*Ws1)[64]) {
    int t = threadIdx.x;
    int m0 = by * 64, o0 = bx * 64;
    int w = t >> 6, lane = t & 63;
    int wm = (w >> 1) * 32, wn = (w & 1) * 32;
    int fr = lane & 15, fq = lane >> 4;
    int srow = lane >> 3;
    int sg   = (lane & 7) ^ srow;
    f32x4 acc[2][2];
#pragma unroll
    for (int mi = 0; mi < 2; mi++)
#pragma unroll
        for (int ni = 0; ni < 2; ni++)
            acc[mi][ni] = f32x4{0.f, 0.f, 0.f, 0.f};

    auto stage = [&](short (*Asb)[64], short (*Wsb)[64], int k0) {
#pragma unroll
        for (int r = 0; r < 2; r++) {
            int rowA = r * 32 + w * 8 + srow;
            gl16(&A[(size_t)(m0 + rowA) * K + k0 + sg * 8], &Asb[r * 32 + w * 8][0]);
            gl16(&W[(size_t)(o0 + rowA) * K + k0 + sg * 8], &Wsb[r * 32 + w * 8][0]);
        }
    };
    auto compute = [&](short (*Asb)[64], short (*Wsb)[64]) {
#pragma unroll
        for (int half = 0; half < 2; half++) {
            bf16x8 af[2], wf[2];
#pragma unroll
            for (int mi = 0; mi < 2; mi++) {
                int row = wm + mi * 16 + fr;
                af[mi] = *(const bf16x8*)&Asb[row][(((half << 2) | fq) ^ (row & 7)) * 8];
            }
#pragma unroll
            for (int ni = 0; ni < 2; ni++) {
                int row = wn + ni * 16 + fr;
                wf[ni] = *(const bf16x8*)&Wsb[row][(((half << 2) | fq) ^ (row & 7)) * 8];
            }
#pragma unroll
            for (int mi = 0; mi < 2; mi++)
#pragma unroll
                for (int ni = 0; ni < 2; ni++)
                    acc[mi][ni] = __builtin_amdgcn_mfma_f32_16x16x32_bf16(
                        af[mi], wf[ni], acc[mi][ni], 0, 0, 0);
        }
    };

    stage(As0, Ws0, 0);
    __syncthreads();
    for (int k0 = 0; k0 < K; k0 += 128) {
        if (k0 + 64 < K) stage(As1, Ws1, k0 + 64);
        compute(As0, Ws0);
        __syncthreads();
        if (k0 + 128 < K) stage(As0, Ws0, k0 + 128);
        if (k0 + 64 < K) compute(As1, Ws1);
        __syncthreads();
    }
#pragma unroll
    for (int mi = 0; mi < 2; mi++)
#pragma unroll
        for (int ni = 0; ni < 2; ni++)
#pragma unroll
            for (int r = 0; r < 4; r++) {
                int m = m0 + wm + mi * 16 + fq * 4 + r;
                int o = o0 + wn + ni * 16 + fr;
                float v = acc[mi][ni][r];
                if (bias) v += bias[o];
                if (RESMODE == 1) v += ((const float*)res)[(size_t)m * O + o];
                if (RESMODE == 2) v += bf2f(((const short*)res)[(size_t)m * O + o]);
                if (OUTB) ((short*)outp)[(size_t)m * O + o] = f2bf(v);
                else      ((float*)outp)[(size_t)m * O + o] = v;
            }
}

// standalone gemm64 kernel (proj, fc2)
template <bool OUTB, int RESMODE>
__global__ __launch_bounds__(256, 4) void gemm64(const short* __restrict__ A,
                                                 const short* __restrict__ W,
                                                 const float* __restrict__ bias,
                                                 const void* __restrict__ res,
                                                 void* __restrict__ outp,
                                                 int M, int O, int K) {
    __shared__ short As0[64][64], Ws0[64][64];
    __shared__ short As1[64][64], Ws1[64][64];
    gemm64_body<OUTB, RESMODE>(A, W, bias, res, outp, M, O, K,
                               blockIdx.x, blockIdx.y, As0, Ws0, As1, Ws1);
}

// ---------------- SR conv body: fused im2col gather (K reordered: k = q*256+c) ----------------
__device__ __forceinline__ void sr_body(const short* __restrict__ xn,
                                        const short* __restrict__ Wsr,
                                        const float* __restrict__ sr_b,
                                        float* __restrict__ srtmp, int bx, int by,
                                        short (*As0)[64], short (*As1)[64],
                                        short (*Ws0)[64], short (*Ws1)[64]) {
    int t = threadIdx.x;
    int m0 = by * 32, o0 = bx * 64;
    int w = t >> 6, lane = t & 63;
    int wm = (w >> 1) * 16, wn = (w & 1) * 32;
    int fr = lane & 15, fq = lane >> 4;
    int srow = lane >> 3;
    int sg   = (lane & 7) ^ srow;
    int arow = w * 8 + srow;
    int p = m0 + arow;
    int b = p >> 10, pp = p & 1023, ii = pp >> 5, jj = pp & 31;
    int nbase = ii * 128 + jj * 2;
    size_t xbase = (size_t)(b * NN) * CCH;
    f32x4 acc[2];
    acc[0] = f32x4{0.f, 0.f, 0.f, 0.f};
    acc[1] = f32x4{0.f, 0.f, 0.f, 0.f};

    auto stage = [&](short (*Asb)[64], short (*Wsb)[64], int k0) {
        int q = k0 >> 8, c0 = k0 & 255;
        int n = nbase + (q >> 1) * 64 + (q & 1);
        gl16(&xn[xbase + (size_t)n * CCH + c0 + sg * 8], &Asb[w * 8][0]);
#pragma unroll
        for (int r = 0; r < 2; r++)
            gl16(&Wsr[(size_t)(o0 + r * 32 + w * 8 + srow) * 1024 + k0 + sg * 8],
                 &Wsb[r * 32 + w * 8][0]);
    };
    auto compute = [&](short (*Asb)[64], short (*Wsb)[64]) {
#pragma unroll
        for (int half = 0; half < 2; half++) {
            int cg = (half << 2) | fq;
            int rowa = wm + fr;
            bf16x8 af = *(const bf16x8*)&Asb[rowa][(cg ^ (rowa & 7)) * 8];
            bf16x8 wf[2];
#pragma unroll
            for (int ni = 0; ni < 2; ni++) {
                int row = wn + ni * 16 + fr;
                wf[ni] = *(const bf16x8*)&Wsb[row][(cg ^ (row & 7)) * 8];
            }
#pragma unroll
            for (int ni = 0; ni < 2; ni++)
                acc[ni] = __builtin_amdgcn_mfma_f32_16x16x32_bf16(
                    af, wf[ni], acc[ni], 0, 0, 0);
        }
    };

    stage(As0, Ws0, 0);
    __syncthreads();
    for (int k0 = 0; k0 < 1024; k0 += 128) {
        if (k0 + 64 < 1024) stage(As1, Ws1, k0 + 64);
        compute(As0, Ws0);
        __syncthreads();
        if (k0 + 128 < 1024) stage(As0, Ws0, k0 + 128);
        compute(As1, Ws1);
        __syncthreads();
    }
#pragma unroll
    for (int ni = 0; ni < 2; ni++)
#pragma unroll
        for (int r = 0; r < 4; r++) {
            int m = m0 + wm + fq * 4 + r;
            int o = o0 + wn + ni * 16 + fr;
            srtmp[(size_t)m * CCH + o] = acc[ni][r] + sr_b[o];
        }
}

// ---------------- merged q-GEMM (blocks 0..511) + sr-GEMM (blocks 512..767) ----------------
__global__ __launch_bounds__(256, 4) void qsr_gemm(const short* __restrict__ xn,
                                                   const short* __restrict__ qwb,
                                                   short* __restrict__ qb,
                                                   const short* __restrict__ srwb,
                                                   const float* __restrict__ sr_b,
                                                   float* __restrict__ srtmp) {
    __shared__ short pool[16384];   // 32 KB
    int i = blockIdx.x;
    if (i < 512) {
        gemm64_body<true, 0>(xn, qwb, nullptr, nullptr, qb, BB * NN, CCH, CCH,
                             i & 3, i >> 2,
                             (short(*)[64])(pool),
                             (short(*)[64])(pool + 4096),
                             (short(*)[64])(pool + 8192),
                             (short(*)[64])(pool + 12288));
    } else {
        i -= 512;
        sr_body(xn, srwb, sr_b, srtmp, i & 3, i >> 2,
                (short(*)[64])(pool),
                (short(*)[64])(pool + 2048),
                (short(*)[64])(pool + 4096),
                (short(*)[64])(pool + 8192));
    }
}

// ---------------- fc1 GEMM, 128x128 tile, BK=64, dbuf ----------------
__global__ __launch_bounds__(256, 2) void gemm_fc1(const short* __restrict__ A,
                                                   const short* __restrict__ W,
                                                   const float* __restrict__ bias,
                                                   short* __restrict__ outp,
                                                   int M, int O, int K) {
    __shared__ short As0[128][64], Ws0[128][64];
    __shared__ short As1[128][64], Ws1[128][64];
    int t = threadIdx.x;
    int m0 = blockIdx.y * 128, o0 = blockIdx.x * 128;
    int w = t >> 6, lane = t & 63;
    int wm = (w >> 1) * 64, wn = (w & 1) * 64;
    int fr = lane & 15, fq = lane >> 4;
    int srow = lane >> 3;
    int sg   = (lane & 7) ^ srow;
    f32x4 acc[4][4];
#pragma unroll
    for (int mi = 0; mi < 4; mi++)
#pragma unroll
        for (int ni = 0; ni < 4; ni++)
            acc[mi][ni] = f32x4{0.f, 0.f, 0.f, 0.f};

    auto stage = [&](short (*Asb)[64], short (*Wsb)[64], int k0) {
#pragma unroll
        for (int r = 0; r < 4; r++) {
            int rowA = r * 32 + w * 8 + srow;
            gl16(&A[(size_t)(m0 + rowA) * K + k0 + sg * 8], &Asb[r * 32 + w * 8][0]);
            gl16(&W[(size_t)(o0 + rowA) * K + k0 + sg * 8], &Wsb[r * 32 + w * 8][0]);
        }
    };
    auto compute = [&](short (*Asb)[64], short (*Wsb)[64]) {
#pragma unroll
        for (int half = 0; half < 2; half++) {
            bf16x8 af[4], wf[4];
#pragma unroll
            for (int mi = 0; mi < 4; mi++) {
                int row = wm + mi * 16 + fr;
                af[mi] = *(const bf16x8*)&Asb[row][(((half << 2) | fq) ^ (row & 7)) * 8];
            }
#pragma unroll
            for (int ni = 0; ni < 4; ni++) {
                int row = wn + ni * 16 + fr;
                wf[ni] = *(const bf16x8*)&Wsb[row][(((half << 2) | fq) ^ (row & 7)) * 8];
            }
#pragma unroll
            for (int mi = 0; mi < 4; mi++)
#pragma unroll
                for (int ni = 0; ni < 4; ni++)
                    acc[mi][ni] = __builtin_amdgcn_mfma_f32_16x16x32_bf16(
                        af[mi], wf[ni], acc[mi][ni], 0, 0, 0);
        }
    };

    stage(As0, Ws0, 0);
    __syncthreads();
    for (int k0 = 0; k0 < K; k0 += 128) {
        if (k0 + 64 < K) stage(As1, Ws1, k0 + 64);
        compute(As0, Ws0);
        __syncthreads();
        if (k0 + 128 < K) stage(As0, Ws0, k0 + 128);
        if (k0 + 64 < K) compute(As1, Ws1);
        __syncthreads();
    }
#pragma unroll
    for (int mi = 0; mi < 4; mi++)
#pragma unroll
        for (int ni = 0; ni < 4; ni++)
#pragma unroll
            for (int r = 0; r < 4; r++) {
                int m = m0 + wm + mi * 16 + fq * 4 + r;
                int o = o0 + wn + ni * 16 + fr;
                outp[(size_t)m * O + o] = f2bf(acc[mi][ni][r] + bias[o]);
            }
}

// ---------------- kv GEMM with fused V-transpose epilogue ----------------
// o<256 -> kvk[m][o] bf16; o>=256 -> vt permuted: within each 64-kv block,
// kv y stored at s=(y&15)*4+(y>>4).
__global__ __launch_bounds__(256, 4) void kv_gemm(const short* __restrict__ A,
                                                  const short* __restrict__ W,
                                                  short* __restrict__ kvk,
                                                  short* __restrict__ vt) {
    __shared__ short As0[64][64], Ws0[64][64];
    __shared__ short As1[64][64], Ws1[64][64];
    int t = threadIdx.x;
    int m0 = blockIdx.y * 64, o0 = blockIdx.x * 64;
    int w = t >> 6, lane = t & 63;
    int wm = (w >> 1) * 32, wn = (w & 1) * 32;
    int fr = lane & 15, fq = lane >> 4;
    int srow = lane >> 3;
    int sg   = (lane & 7) ^ srow;
    f32x4 acc[2][2];
#pragma unroll
    for (int mi = 0; mi < 2; mi++)
#pragma unroll
        for (int ni = 0; ni < 2; ni++)
            acc[mi][ni] = f32x4{0.f, 0.f, 0.f, 0.f};

    auto stage = [&](short (*Asb)[64], short (*Wsb)[64], int k0) {
#pragma unroll
        for (int r = 0; r < 2; r++) {
            int rowA = r * 32 + w * 8 + srow;
            gl16(&A[(size_t)(m0 + rowA) * CCH + k0 + sg * 8], &Asb[r * 32 + w * 8][0]);
            gl16(&W[(size_t)(o0 + rowA) * CCH + k0 + sg * 8], &Wsb[r * 32 + w * 8][0]);
        }
    };
    auto compute = [&](short (*Asb)[64], short (*Wsb)[64]) {
#pragma unroll
        for (int half = 0; half < 2; half++) {
            bf16x8 af[2], wf[2];
#pragma unroll
            for (int mi = 0; mi < 2; mi++) {
                int row = wm + mi * 16 + fr;
                af[mi] = *(const bf16x8*)&Asb[row][(((half << 2) | fq) ^ (row & 7)) * 8];
            }
#pragma unroll
            for (int ni = 0; ni < 2; ni++) {
                int row = wn + ni * 16 + fr;
                wf[ni] = *(const bf16x8*)&Wsb[row][(((half << 2) | fq) ^ (row & 7)) * 8];
            }
#pragma unroll
            for (int mi = 0; mi < 2; mi++)
#pragma unroll
                for (int ni = 0; ni < 2; ni++)
                    acc[mi][ni] = __builtin_amdgcn_mfma_f32_16x16x32_bf16(
                        af[mi], wf[ni], acc[mi][ni], 0, 0, 0);
        }
    };

    stage(As0, Ws0, 0);
    __syncthreads();
    stage(As1, Ws1, 64);
    compute(As0, Ws0);
    __syncthreads();
    stage(As0, Ws0, 128);
    compute(As1, Ws1);
    __syncthreads();
    stage(As1, Ws1, 192);
    compute(As0, Ws0);
    __syncthreads();
    compute(As1, Ws1);

#pragma unroll
    for (int mi = 0; mi < 2; mi++)
#pragma unroll
        for (int ni = 0; ni < 2; ni++) {
            int o = o0 + wn + ni * 16 + fr;
            int mbase = m0 + wm + mi * 16 + fq * 4;
            if (o < 256) {
#pragma unroll
                for (int r = 0; r < 4; r++)
                    kvk[(size_t)(mbase + r) * 256 + o] = f2bf(acc[mi][ni][r]);
            } else {
                int h = (o - 256) >> 5, d = (o - 256) & 31;
                int b = mbase >> 10, y0 = mbase & 1023;
                size_t rowbase = ((size_t)((b * NH + h) * HD) + d) * NKV + (y0 >> 6) * 64;
                int y4 = y0 & 63;
#pragma unroll
                for (int r = 0; r < 4; r++) {
                    int y64 = y4 + r;
                    int s = (y64 & 15) * 4 + (y64 >> 4);
                    vt[rowbase + s] = f2bf(acc[mi][ni][r]);
                }
            }
        }
}

// ---------------- MFMA flash attention: 64 q rows/block, pi-permuted P, 4 blocks/CU ----------------
__global__ __launch_bounds__(256, 4) void attn_mfma(const short* __restrict__ qb,
                                                    const short* __restrict__ kvk,
                                                    const short* __restrict__ vt,
                                                    short* __restrict__ o) {
    int blk = blockIdx.x;
    int qt = blk & 63; int hh = (blk >> 6) & 7; int b = blk >> 9;
    int t = threadIdx.x; int w = t >> 6; int lane = t & 63;
    int fr = lane & 15, fq = lane >> 4;
    __shared__ short Ks0[128][32], Ks1[128][32];   // 8 KB each
    __shared__ short Vt0[64][64],  Vt1[64][64];    // 8 KB each (permuted kv positions)
    __shared__ short Ps[4][16][64];                // 8 KB, per-wave, permuted
    int n0 = qt * 64 + w * 16;
    bf16x8 qa = *(const bf16x8*)&qb[((size_t)(b * NN) + n0 + fr) * CCH + hh * HD + fq * 8];
    f32x4 oacc[2];
    float lst[4] = {0.f, 0.f, 0.f, 0.f};
#pragma unroll
    for (int nd = 0; nd < 2; nd++) oacc[nd] = f32x4{0.f, 0.f, 0.f, 0.f};

    int srowK = lane >> 2;                    // 0..15 (64B rows)
    int sgK   = (lane & 3) ^ (srowK & 3);
    int srowV = lane >> 3;                    // 0..7 (128B rows)
    int sgV   = (lane & 7) ^ srowV;

    auto stageKV = [&](short (*Ksb)[32], short (*Vtb)[64], int y0) {
#pragma unroll
        for (int r2 = 0; r2 < 2; r2++) {
            int rowK = r2 * 64 + w * 16 + srowK;
            gl16(&kvk[((size_t)(b * NKV) + y0 + rowK) * 256 + hh * HD + sgK * 8],
                 &Ksb[r2 * 64 + w * 16][0]);
        }
#pragma unroll
        for (int r3 = 0; r3 < 2; r3++) {
            int d = w * 8 + srowV;
            gl16(&vt[((size_t)((b * NH + hh) * HD) + d) * NKV + y0 + r3 * 64 + sgV * 8],
                 &Vtb[r3 * 32 + w * 8][0]);
        }
    };
    auto tile = [&](short (*Ksb)[32], short (*Vtb)[64]) {
#pragma unroll
        for (int h2 = 0; h2 < 2; h2++) {
            f32x4 s[4];
            __builtin_amdgcn_s_setprio(1);
#pragma unroll
            for (int ni = 0; ni < 4; ni++) {
                int rowk = h2 * 64 + ni * 16 + fr;
                bf16x8 kb = *(const bf16x8*)&Ksb[rowk][(fq ^ (fr & 3)) * 8];
                s[ni] = __builtin_amdgcn_mfma_f32_16x16x32_bf16(
                    qa, kb, f32x4{0.f, 0.f, 0.f, 0.f}, 0, 0, 0);
            }
            __builtin_amdgcn_s_setprio(0);
            // P: exp, pack 4 bf16, single b64 store at permuted position
            // s(col)=(col&15)*4+(col>>4): lane's cols {i*16+fr} -> slots fr*4+i
#pragma unroll
            for (int r = 0; r < 4; r++) {
                int row = fq * 4 + r;
                float p0 = __expf(fminf(s[0][r], 30.f));
                float p1 = __expf(fminf(s[1][r], 30.f));
                float p2 = __expf(fminf(s[2][r], 30.f));
                float p3 = __expf(fminf(s[3][r], 30.f));
                lst[r] += (p0 + p1) + (p2 + p3);
                unsigned int w0 = cvtpk_bf16(p0, p1);
                unsigned int w1 = cvtpk_bf16(p2, p3);
                int gp = (fr >> 1) ^ (row & 7);     // 16B-group swizzle
                *(uint2*)&Ps[w][row][gp * 8 + (fr & 1) * 4] = make_uint2(w0, w1);
            }
            __builtin_amdgcn_s_setprio(1);
#pragma unroll
            for (int ks = 0; ks < 2; ks++) {
                int gk = ks * 4 + fq;               // slot group 0..7
                bf16x8 pa = *(const bf16x8*)&Ps[w][fr][(gk ^ (fr & 7)) * 8];
#pragma unroll
                for (int nd = 0; nd < 2; nd++) {
                    int rowv = nd * 16 + fr;
                    bf16x8 vb = *(const bf16x8*)&Vtb[h2 * 32 + rowv][(gk ^ (rowv & 7)) * 8];
                    oacc[nd] = __builtin_amdgcn_mfma_f32_16x16x32_bf16(
                        pa, vb, oacc[nd], 0, 0, 0);
                }
            }
            __builtin_amdgcn_s_setprio(0);
        }
    };

    stageKV(Ks0, Vt0, 0);
    __syncthreads();
    for (int y0 = 0; y0 < NKV; y0 += 256) {
        if (y0 + 128 < NKV) stageKV(Ks1, Vt1, y0 + 128);   // issue early
        tile(Ks0, Vt0);
        __syncthreads();                                   // wait late
        if (y0 + 256 < NKV) stageKV(Ks0, Vt0, y0 + 256);
        tile(Ks1, Vt1);
        __syncthreads();
    }
#pragma unroll
    for (int r = 0; r < 4; r++) {
        float ls = lst[r];
#pragma unroll
        for (int off = 1; off < 16; off <<= 1)
            ls += __shfl_xor(ls, off);
        float inv = 1.f / ls;
        int row = n0 + fq * 4 + r;
#pragma unroll
        for (int nd = 0; nd < 2; nd++)
            o[((size_t)(b * NN) + row) * CCH + hh * HD + nd * 16 + fr] =
                f2bf(oacc[nd][r] * inv);
    }
}

// ---------------- depthwise 3x3 + bias + tanh-GELU, bf16 in/out ----------------
__global__ __launch_bounds__(256, 2) void dwconv_gelu(const short* __restrict__ xf,
                                                      const float* __restrict__ pe_w,
                                                      const float* __restrict__ pe_b,
                                                      short* __restrict__ out) {
    int blk = blockIdx.x;
    int cg = blk & 15, sp = (blk >> 4) & 15, b = blk >> 8;
    int r0 = (sp >> 2) * 16, c0 = (sp & 3) * 16;
    int ch0 = cg * 64;
    int t = threadIdx.x;
    __shared__ short tile[18][18][64];
    for (int idx = t; idx < 18 * 18 * 8; idx += 256) {
        int pix = idx >> 3, part = idx & 7;
        int row = pix / 18, col = pix - row * 18;
        int gr = r0 + row - 1, gc = c0 + col - 1;
        bf16x8 v = {0, 0, 0, 0, 0, 0, 0, 0};
        if (gr >= 0 && gr < 64 && gc >= 0 && gc < 64)
            v = *(const bf16x8*)&xf[((size_t)(b * NN) + gr * GW + gc) * HIDN + ch0 + part * 8];
        *(bf16x8*)&tile[row][col][part * 8] = v;
    }
    __syncthreads();
    int cl = t & 63, sg = t >> 6;
    int ch = ch0 + cl;
    float wv[9];
#pragma unroll
    for (int k = 0; k < 9; k++) wv[k] = pe_w[ch * 9 + k];
    float bias = pe_b[ch];
#pragma unroll
    for (int q = 0; q < 4; q++) {
        int lr = sg * 4 + q;
        float cA[3], cB[3], cC[3];
#pragma unroll
        for (int ki = 0; ki < 3; ki++) {
            cA[ki] = bf2f(tile[lr + ki][0][cl]);
            cB[ki] = bf2f(tile[lr + ki][1][cl]);
        }
        for (int cc = 0; cc < 16; cc++) {
#pragma unroll
            for (int ki = 0; ki < 3; ki++) cC[ki] = bf2f(tile[lr + ki][cc + 2][cl]);
            float acc = bias;
#pragma unroll
            for (int ki = 0; ki < 3; ki++)
                acc += cA[ki] * wv[ki * 3] + cB[ki] * wv[ki * 3 + 1] + cC[ki] * wv[ki * 3 + 2];
            float z = 0.7978845608f * (acc + 0.044715f * acc * acc * acc);
            float e = __expf(-2.f * fabsf(z));
            float th = (1.f - e) / (1.f + e);
            th = (z < 0.f) ? -th : th;
            float gg = 0.5f * acc * (1.f + th);
            out[((size_t)(b * NN) + (r0 + lr) * GW + c0 + cc) * HIDN + ch] = f2bf(gg);
#pragma unroll
            for (int ki = 0; ki < 3; ki++) { cA[ki] = cB[ki]; cB[ki] = cC[ki]; }
        }
    }
}

extern "C" void kernel_launch(void* const* d_in, const int* in_sizes, int n_in,
                              void* d_out, int out_size, void* d_ws, size_t ws_size,
                              hipStream_t stream) {
    const float* x      = (const float*)d_in[0];
    const float* ln1_g  = (const float*)d_in[3];
    const float* ln1_b  = (const float*)d_in[4];
    const float* q_w    = (const float*)d_in[5];
    const float* kv_w   = (const float*)d_in[6];
    const float* sr_w   = (const float*)d_in[7];
    const float* sr_b   = (const float*)d_in[8];
    const float* srn_g  = (const float*)d_in[9];
    const float* srn_b  = (const float*)d_in[10];
    const float* proj_w = (const float*)d_in[11];
    const float* proj_b = (const float*)d_in[12];
    const float* ln2_g  = (const float*)d_in[13];
    const float* ln2_b  = (const float*)d_in[14];
    const float* fc1_w  = (const float*)d_in[15];
    const float* fc1_b  = (const float*)d_in[16];
    const float* pe_w   = (const float*)d_in[17];
    const float* pe_b   = (const float*)d_in[18];
    const float* fc2_w  = (const float*)d_in[19];
    const float* fc2_b  = (const float*)d_in[20];
    float* out = (float*)d_out;

    // workspace carve (bytes)
    char* base = (char*)d_ws;
    short* xn    = (short*)(base);                   // [0,4M)   xn / xn2 bf16
    short* qb    = (short*)(base + (4ull  << 20));   // [4,8)    q bf16 (pre-scaled)
    float* srtmp = (float*)(base + (12ull << 20));   // [12,14)  sr conv out f32 [2048][256]
    short* xkvn  = (short*)(base + (14ull << 20));   // [14,15)  x_kvn bf16
    short* kvk   = (short*)(base + (15ull << 20));   // [15,16)  k bf16 [2048][256]
    short* vtb   = (short*)(base + (17ull << 20));   // [17,18)  V^T bf16 [512][1024] (permuted)
    short* obf   = (short*)(base + (18ull << 20));   // [18,22)  attn out bf16
    short* x1    = (short*)(base + (22ull << 20));   // [22,26)  x1 bf16
    short* xf1   = (short*)(base + (30ull << 20));   // [30,46)  fc1 out bf16 [8192][1024]
    short* xf2g  = (short*)(base + (46ull << 20));   // [46,62)  gelu(dwconv) bf16
    short* qwb   = (short*)(base + (62ull << 20));   // weights bf16
    short* kvwb  = qwb  + 65536;
    short* pjwb  = kvwb + 131072;
    short* f1wb  = pjwb + 65536;
    short* f2wb  = f1wb + 262144;
    short* srwb  = f2wb + 262144;

    // 0. weights -> bf16 (sr reordered) + LN1, one launch
    prep_kernel<<<4096 + BB * NN, 256, 0, stream>>>(q_w, kv_w, proj_w, fc1_w, fc2_w, sr_w,
                                                    qwb, kvwb, pjwb, f1wb, f2wb, srwb,
                                                    x, ln1_g, ln1_b, xn);
    // 2+3. q-GEMM and sr-GEMM merged
    qsr_gemm<<<768, 256, 0, stream>>>(xn, qwb, qb, srwb, sr_b, srtmp);
    // 3c. x_kvn = LN(srtmp)
    ln_wave<false><<<BB * NKV / 4, 256, 0, stream>>>(srtmp, srn_g, srn_b, xkvn);
    // 4. kv = x_kvn . kv_w^T -> kvk (k half) + vtb (v half, transposed+permuted)
    {
        dim3 g(512 / 64, (BB * NKV) / 64);
        kv_gemm<<<g, 256, 0, stream>>>(xkvn, kvwb, kvk, vtb);
    }
    // 5. attention -> obf (64 q rows/block, 4 blocks/CU)
    attn_mfma<<<BB * NH * (NN / 64), 256, 0, stream>>>(qb, kvk, vtb, obf);
    // 6. x1 = x + obf . proj_w^T + proj_b  (bf16 out)
    {
        dim3 g(CCH / 64, (BB * NN) / 64);
        gemm64<true, 1><<<g, 256, 0, stream>>>(obf, pjwb, proj_b, x, x1, BB * NN, CCH, CCH);
    }
    // 7. xn2 = LN2(x1) (bf16 in, reuse xn)
    ln_wave<true><<<BB * NN / 4, 256, 0, stream>>>(x1, ln2_g, ln2_b, xn);
    // 8. xf1 = xn2 . fc1_w^T + fc1_b  (bf16 out, 128x128 tile)
    {
        dim3 g(HIDN / 128, (BB * NN) / 128);
        gemm_fc1<<<g, 256, 0, stream>>>(xn, f1wb, fc1_b, xf1, BB * NN, HIDN, CCH);
    }
    // 9. xf2g = gelu(dwconv3x3(xf1) + pe_b)
    dwconv_gelu<<<BB * 256, 256, 0, stream>>>(xf1, pe_w, pe_b, xf2g);
    // 10. out = x1 + xf2g . fc2_w^T + fc2_b  (f32)
    {
        dim3 g(CCH / 64, (BB * NN) / 64);
        gemm64<false, 2><<<g, 256, 0, stream>>>(xf2g, f2wb, fc2_b, x1, out, BB * NN, CCH, HIDN);
    }
}

// Round 17
// 110.678 us; speedup vs baseline: 1.0956x; 1.0227x over previous
//
#include <hip/hip_runtime.h>
#include <math.h>

// problem constants
constexpr int BB   = 2;
constexpr int NN   = 4096;
constexpr int CCH  = 256;   // channels
constexpr int NH   = 8;     // heads
constexpr int HD   = 32;    // head dim
constexpr int GW   = 64;    // spatial h = w
constexpr int NKV  = 1024;  // (64/2)*(64/2)
constexpr int HIDN = 1024;
constexpr float EPSF = 1e-5f;

typedef short  bf16x8 __attribute__((ext_vector_type(8)));
typedef short  bf16x4 __attribute__((ext_vector_type(4)));
typedef float  f32x4  __attribute__((ext_vector_type(4)));

__device__ __forceinline__ short f2bf(float f) {
    unsigned int u = __float_as_uint(f);
    unsigned int r = (u + 0x7FFFu + ((u >> 16) & 1u)) >> 16;   // RNE
    return (short)r;
}
__device__ __forceinline__ float bf2f(short s) {
    return __uint_as_float(((unsigned int)(unsigned short)s) << 16);
}
// packed f32x2 -> bf16x2 (RNE), src0 -> low half
__device__ __forceinline__ unsigned int cvtpk_bf16(float a, float b) {
    unsigned int r;
    asm("v_cvt_pk_bf16_f32 %0, %1, %2" : "=v"(r) : "v"(a), "v"(b));
    return r;
}
// async global->LDS, 16B per lane; lds base must be wave-uniform (HW adds lane*16)
__device__ __forceinline__ void gl16(const void* g, void* l) {
    __builtin_amdgcn_global_load_lds(
        (const __attribute__((address_space(1))) void*)g,
        (__attribute__((address_space(3))) void*)l, 16, 0, 0);
}

// ---------------- prep: weight cvt (blocks 0..4095) + x->bf16 (4096..6143)
//                  + LN1 wave-per-row (6144..8191; 4 rows/block) ----------------
// sr_w reordered: srwb[o][q*256+c] = sr_w[o][c*4+q]  (K-dim quad-major)
__global__ __launch_bounds__(256) void prep_kernel(const float* __restrict__ q_w,
                                                   const float* __restrict__ kv_w,
                                                   const float* __restrict__ proj_w,
                                                   const float* __restrict__ fc1_w,
                                                   const float* __restrict__ fc2_w,
                                                   const float* __restrict__ sr_w,
                                                   short* qwb, short* kvwb, short* pjwb,
                                                   short* f1wb, short* f2wb, short* srwb,
                                                   const float* __restrict__ x,
                                                   const float* __restrict__ ln1_g,
                                                   const float* __restrict__ ln1_b,
                                                   short* __restrict__ xn,
                                                   short* __restrict__ xbf) {
    int t = threadIdx.x;
    if (blockIdx.x < 4096) {
        int i = blockIdx.x * 256 + t;
        if (i < 65536) { qwb[i] = f2bf(q_w[i] * 0.17677669529663687f); return; }
        i -= 65536;
        if (i < 131072) { kvwb[i] = f2bf(kv_w[i]); return; }
        i -= 131072;
        if (i < 65536) { pjwb[i] = f2bf(proj_w[i]); return; }
        i -= 65536;
        if (i < 262144) { f1wb[i] = f2bf(fc1_w[i]); return; }
        i -= 262144;
        if (i < 262144) { f2wb[i] = f2bf(fc2_w[i]); return; }
        i -= 262144;
        {
            int o = i >> 10, rem = i & 1023, c = rem >> 2, q = rem & 3;
            srwb[o * 1024 + q * 256 + c] = f2bf(sr_w[i]);
        }
        return;
    }
    if (blockIdx.x < 6144) {
        // x -> bf16 copy (for proj residual), 1024 f32/block
        size_t i = (size_t)(blockIdx.x - 4096) * 1024 + t * 4;
        float4 fv = *(const float4*)&x[i];
        bf16x4 ov;
        ov[0] = f2bf(fv.x); ov[1] = f2bf(fv.y); ov[2] = f2bf(fv.z); ov[3] = f2bf(fv.w);
        *(bf16x4*)&xbf[i] = ov;
        return;
    }
    // LN1, wave-per-row: 4 rows/block
    int w = t >> 6, lane = t & 63;
    int row = (blockIdx.x - 6144) * 4 + w;
    float4 fv = *(const float4*)&x[(size_t)row * CCH + lane * 4];
    float v[4] = {fv.x, fv.y, fv.z, fv.w};
    float a = v[0] + v[1] + v[2] + v[3];
    float b = v[0]*v[0] + v[1]*v[1] + v[2]*v[2] + v[3]*v[3];
#pragma unroll
    for (int off = 1; off < 64; off <<= 1) {
        a += __shfl_xor(a, off);
        b += __shfl_xor(b, off);
    }
    float mu = a * (1.0f / CCH);
    float var = b * (1.0f / CCH) - mu * mu;
    float rs = rsqrtf(var + EPSF);
    bf16x4 ov;
#pragma unroll
    for (int j = 0; j < 4; j++)
        ov[j] = f2bf((v[j] - mu) * rs * ln1_g[lane * 4 + j] + ln1_b[lane * 4 + j]);
    *(bf16x4*)&xn[(size_t)row * CCH + lane * 4] = ov;
}

// ---------------- wave-per-row LayerNorm (C=256): 4 rows/block, no barriers ----------------
template <bool INBF>
__global__ __launch_bounds__(256) void ln_wave(const void* __restrict__ in,
                                               const float* __restrict__ g,
                                               const float* __restrict__ bta,
                                               short* __restrict__ out) {
    int t = threadIdx.x;
    int w = t >> 6, lane = t & 63;
    int row = blockIdx.x * 4 + w;
    float v[4];
    if (INBF) {
        bf16x4 bv = *(const bf16x4*)&((const short*)in)[(size_t)row * CCH + lane * 4];
#pragma unroll
        for (int j = 0; j < 4; j++) v[j] = bf2f(bv[j]);
    } else {
        float4 fv = *(const float4*)&((const float*)in)[(size_t)row * CCH + lane * 4];
        v[0] = fv.x; v[1] = fv.y; v[2] = fv.z; v[3] = fv.w;
    }
    float a = v[0] + v[1] + v[2] + v[3];
    float b = v[0]*v[0] + v[1]*v[1] + v[2]*v[2] + v[3]*v[3];
#pragma unroll
    for (int off = 1; off < 64; off <<= 1) {
        a += __shfl_xor(a, off);
        b += __shfl_xor(b, off);
    }
    float mu = a * (1.0f / CCH);
    float var = b * (1.0f / CCH) - mu * mu;
    float rs = rsqrtf(var + EPSF);
    bf16x4 ov;
#pragma unroll
    for (int j = 0; j < 4; j++)
        ov[j] = f2bf((v[j] - mu) * rs * g[lane * 4 + j] + bta[lane * 4 + j]);
    *(bf16x4*)&out[(size_t)row * CCH + lane * 4] = ov;
}

// ---------------- gemm64 body (device fn): 64x64 tile, BK=64, 2-phase dbuf ----------------
template <bool OUTB, int RESMODE>
__device__ __forceinline__ void gemm64_body(const short* __restrict__ A,
                                            const short* __restrict__ W,
                                            const float* __restrict__ bias,
                                            const void* __restrict__ res,
                                            void* __restrict__ outp,
                                            int M, int O, int K, int bx, int by,
                                            short (*As0)[64], short (*Ws0)[64],
                                            short (*As1)[64], short (*Ws1)[64]) {
    int t = threadIdx.x;
    int m0 = by * 64, o0 = bx * 64;
    int w = t >> 6, lane = t & 63;
    int wm = (w >> 1) * 32, wn = (w & 1) * 32;
    int fr = lane & 15, fq = lane >> 4;
    int srow = lane >> 3;
    int sg   = (lane & 7) ^ srow;
    f32x4 acc[2][2];
#pragma unroll
    for (int mi = 0; mi < 2; mi++)
#pragma unroll
        for (int ni = 0; ni < 2; ni++)
            acc[mi][ni] = f32x4{0.f, 0.f, 0.f, 0.f};

    auto stage = [&](short (*Asb)[64], short (*Wsb)[64], int k0) {
#pragma unroll
        for (int r = 0; r < 2; r++) {
            int rowA = r * 32 + w * 8 + srow;
            gl16(&A[(size_t)(m0 + rowA) * K + k0 + sg * 8], &Asb[r * 32 + w * 8][0]);
            gl16(&W[(size_t)(o0 + rowA) * K + k0 + sg * 8], &Wsb[r * 32 + w * 8][0]);
        }
    };
    auto compute = [&](short (*Asb)[64], short (*Wsb)[64]) {
#pragma unroll
        for (int half = 0; half < 2; half++) {
            bf16x8 af[2], wf[2];
#pragma unroll
            for (int mi = 0; mi < 2; mi++) {
                int row = wm + mi * 16 + fr;
                af[mi] = *(const bf16x8*)&Asb[row][(((half << 2) | fq) ^ (row & 7)) * 8];
            }
#pragma unroll
            for (int ni = 0; ni < 2; ni++) {
                int row = wn + ni * 16 + fr;
                wf[ni] = *(const bf16x8*)&Wsb[row][(((half << 2) | fq) ^ (row & 7)) * 8];
            }
#pragma unroll
            for (int mi = 0; mi < 2; mi++)
#pragma unroll
                for (int ni = 0; ni < 2; ni++)
                    acc[mi][ni] = __builtin_amdgcn_mfma_f32_16x16x32_bf16(
                        af[mi], wf[ni], acc[mi][ni], 0, 0, 0);
        }
    };

    stage(As0, Ws0, 0);
    __syncthreads();
    for (int k0 = 0; k0 < K; k0 += 128) {
        if (k0 + 64 < K) stage(As1, Ws1, k0 + 64);
        compute(As0, Ws0);
        __syncthreads();
        if (k0 + 128 < K) stage(As0, Ws0, k0 + 128);
        if (k0 + 64 < K) compute(As1, Ws1);
        __syncthreads();
    }
#pragma unroll
    for (int mi = 0; mi < 2; mi++)
#pragma unroll
        for (int ni = 0; ni < 2; ni++)
#pragma unroll
            for (int r = 0; r < 4; r++) {
                int m = m0 + wm + mi * 16 + fq * 4 + r;
                int o = o0 + wn + ni * 16 + fr;
                float v = acc[mi][ni][r];
                if (bias) v += bias[o];
                if (RESMODE == 1) v += ((const float*)res)[(size_t)m * O + o];
                if (RESMODE == 2) v += bf2f(((const short*)res)[(size_t)m * O + o]);
                if (OUTB) ((short*)outp)[(size_t)m * O + o] = f2bf(v);
                else      ((float*)outp)[(size_t)m * O + o] = v;
            }
}

// standalone gemm64 kernel (proj, fc2)
template <bool OUTB, int RESMODE>
__global__ __launch_bounds__(256, 4) void gemm64(const short* __restrict__ A,
                                                 const short* __restrict__ W,
                                                 const float* __restrict__ bias,
                                                 const void* __restrict__ res,
                                                 void* __restrict__ outp,
                                                 int M, int O, int K) {
    __shared__ short As0[64][64], Ws0[64][64];
    __shared__ short As1[64][64], Ws1[64][64];
    gemm64_body<OUTB, RESMODE>(A, W, bias, res, outp, M, O, K,
                               blockIdx.x, blockIdx.y, As0, Ws0, As1, Ws1);
}

// ---------------- SR conv body: fused im2col gather (K reordered: k = q*256+c) ----------------
__device__ __forceinline__ void sr_body(const short* __restrict__ xn,
                                        const short* __restrict__ Wsr,
                                        const float* __restrict__ sr_b,
                                        float* __restrict__ srtmp, int bx, int by,
                                        short (*As0)[64], short (*As1)[64],
                                        short (*Ws0)[64], short (*Ws1)[64]) {
    int t = threadIdx.x;
    int m0 = by * 32, o0 = bx * 64;
    int w = t >> 6, lane = t & 63;
    int wm = (w >> 1) * 16, wn = (w & 1) * 32;
    int fr = lane & 15, fq = lane >> 4;
    int srow = lane >> 3;
    int sg   = (lane & 7) ^ srow;
    int arow = w * 8 + srow;
    int p = m0 + arow;
    int b = p >> 10, pp = p & 1023, ii = pp >> 5, jj = pp & 31;
    int nbase = ii * 128 + jj * 2;
    size_t xbase = (size_t)(b * NN) * CCH;
    f32x4 acc[2];
    acc[0] = f32x4{0.f, 0.f, 0.f, 0.f};
    acc[1] = f32x4{0.f, 0.f, 0.f, 0.f};

    auto stage = [&](short (*Asb)[64], short (*Wsb)[64], int k0) {
        int q = k0 >> 8, c0 = k0 & 255;
        int n = nbase + (q >> 1) * 64 + (q & 1);
        gl16(&xn[xbase + (size_t)n * CCH + c0 + sg * 8], &Asb[w * 8][0]);
#pragma unroll
        for (int r = 0; r < 2; r++)
            gl16(&Wsr[(size_t)(o0 + r * 32 + w * 8 + srow) * 1024 + k0 + sg * 8],
                 &Wsb[r * 32 + w * 8][0]);
    };
    auto compute = [&](short (*Asb)[64], short (*Wsb)[64]) {
#pragma unroll
        for (int half = 0; half < 2; half++) {
            int cg = (half << 2) | fq;
            int rowa = wm + fr;
            bf16x8 af = *(const bf16x8*)&Asb[rowa][(cg ^ (rowa & 7)) * 8];
            bf16x8 wf[2];
#pragma unroll
            for (int ni = 0; ni < 2; ni++) {
                int row = wn + ni * 16 + fr;
                wf[ni] = *(const bf16x8*)&Wsb[row][(cg ^ (row & 7)) * 8];
            }
#pragma unroll
            for (int ni = 0; ni < 2; ni++)
                acc[ni] = __builtin_amdgcn_mfma_f32_16x16x32_bf16(
                    af, wf[ni], acc[ni], 0, 0, 0);
        }
    };

    stage(As0, Ws0, 0);
    __syncthreads();
    for (int k0 = 0; k0 < 1024; k0 += 128) {
        if (k0 + 64 < 1024) stage(As1, Ws1, k0 + 64);
        compute(As0, Ws0);
        __syncthreads();
        if (k0 + 128 < 1024) stage(As0, Ws0, k0 + 128);
        compute(As1, Ws1);
        __syncthreads();
    }
#pragma unroll
    for (int ni = 0; ni < 2; ni++)
#pragma unroll
        for (int r = 0; r < 4; r++) {
            int m = m0 + wm + fq * 4 + r;
            int o = o0 + wn + ni * 16 + fr;
            srtmp[(size_t)m * CCH + o] = acc[ni][r] + sr_b[o];
        }
}

// ---------------- merged q-GEMM (blocks 0..511) + sr-GEMM (blocks 512..767) ----------------
__global__ __launch_bounds__(256, 4) void qsr_gemm(const short* __restrict__ xn,
                                                   const short* __restrict__ qwb,
                                                   short* __restrict__ qb,
                                                   const short* __restrict__ srwb,
                                                   const float* __restrict__ sr_b,
                                                   float* __restrict__ srtmp) {
    __shared__ short pool[16384];   // 32 KB
    int i = blockIdx.x;
    if (i < 512) {
        gemm64_body<true, 0>(xn, qwb, nullptr, nullptr, qb, BB * NN, CCH, CCH,
                             i & 3, i >> 2,
                             (short(*)[64])(pool),
                             (short(*)[64])(pool + 4096),
                             (short(*)[64])(pool + 8192),
                             (short(*)[64])(pool + 12288));
    } else {
        i -= 512;
        sr_body(xn, srwb, sr_b, srtmp, i & 3, i >> 2,
                (short(*)[64])(pool),
                (short(*)[64])(pool + 2048),
                (short(*)[64])(pool + 4096),
                (short(*)[64])(pool + 8192));
    }
}

// ---------------- fc1 GEMM, 128x128 tile, BK=64, dbuf ----------------
__global__ __launch_bounds__(256, 2) void gemm_fc1(const short* __restrict__ A,
                                                   const short* __restrict__ W,
                                                   const float* __restrict__ bias,
                                                   short* __restrict__ outp,
                                                   int M, int O, int K) {
    __shared__ short As0[128][64], Ws0[128][64];
    __shared__ short As1[128][64], Ws1[128][64];
    int t = threadIdx.x;
    int m0 = blockIdx.y * 128, o0 = blockIdx.x * 128;
    int w = t >> 6, lane = t & 63;
    int wm = (w >> 1) * 64, wn = (w & 1) * 64;
    int fr = lane & 15, fq = lane >> 4;
    int srow = lane >> 3;
    int sg   = (lane & 7) ^ srow;
    f32x4 acc[4][4];
#pragma unroll
    for (int mi = 0; mi < 4; mi++)
#pragma unroll
        for (int ni = 0; ni < 4; ni++)
            acc[mi][ni] = f32x4{0.f, 0.f, 0.f, 0.f};

    auto stage = [&](short (*Asb)[64], short (*Wsb)[64], int k0) {
#pragma unroll
        for (int r = 0; r < 4; r++) {
            int rowA = r * 32 + w * 8 + srow;
            gl16(&A[(size_t)(m0 + rowA) * K + k0 + sg * 8], &Asb[r * 32 + w * 8][0]);
            gl16(&W[(size_t)(o0 + rowA) * K + k0 + sg * 8], &Wsb[r * 32 + w * 8][0]);
        }
    };
    auto compute = [&](short (*Asb)[64], short (*Wsb)[64]) {
#pragma unroll
        for (int half = 0; half < 2; half++) {
            bf16x8 af[4], wf[4];
#pragma unroll
            for (int mi = 0; mi < 4; mi++) {
                int row = wm + mi * 16 + fr;
                af[mi] = *(const bf16x8*)&Asb[row][(((half << 2) | fq) ^ (row & 7)) * 8];
            }
#pragma unroll
            for (int ni = 0; ni < 4; ni++) {
                int row = wn + ni * 16 + fr;
                wf[ni] = *(const bf16x8*)&Wsb[row][(((half << 2) | fq) ^ (row & 7)) * 8];
            }
#pragma unroll
            for (int mi = 0; mi < 4; mi++)
#pragma unroll
                for (int ni = 0; ni < 4; ni++)
                    acc[mi][ni] = __builtin_amdgcn_mfma_f32_16x16x32_bf16(
                        af[mi], wf[ni], acc[mi][ni], 0, 0, 0);
        }
    };

    stage(As0, Ws0, 0);
    __syncthreads();
    for (int k0 = 0; k0 < K; k0 += 128) {
        if (k0 + 64 < K) stage(As1, Ws1, k0 + 64);
        compute(As0, Ws0);
        __syncthreads();
        if (k0 + 128 < K) stage(As0, Ws0, k0 + 128);
        if (k0 + 64 < K) compute(As1, Ws1);
        __syncthreads();
    }
#pragma unroll
    for (int mi = 0; mi < 4; mi++)
#pragma unroll
        for (int ni = 0; ni < 4; ni++)
#pragma unroll
            for (int r = 0; r < 4; r++) {
                int m = m0 + wm + mi * 16 + fq * 4 + r;
                int o = o0 + wn + ni * 16 + fr;
                outp[(size_t)m * O + o] = f2bf(acc[mi][ni][r] + bias[o]);
            }
}

// ---------------- kv GEMM with fused V-transpose epilogue ----------------
// o<256 -> kvk[m][o] bf16; o>=256 -> vt permuted: within each 64-kv block,
// kv y stored at s=(y&15)*4+(y>>4).
__global__ __launch_bounds__(256, 4) void kv_gemm(const short* __restrict__ A,
                                                  const short* __restrict__ W,
                                                  short* __restrict__ kvk,
                                                  short* __restrict__ vt) {
    __shared__ short As0[64][64], Ws0[64][64];
    __shared__ short As1[64][64], Ws1[64][64];
    int t = threadIdx.x;
    int m0 = blockIdx.y * 64, o0 = blockIdx.x * 64;
    int w = t >> 6, lane = t & 63;
    int wm = (w >> 1) * 32, wn = (w & 1) * 32;
    int fr = lane & 15, fq = lane >> 4;
    int srow = lane >> 3;
    int sg   = (lane & 7) ^ srow;
    f32x4 acc[2][2];
#pragma unroll
    for (int mi = 0; mi < 2; mi++)
#pragma unroll
        for (int ni = 0; ni < 2; ni++)
            acc[mi][ni] = f32x4{0.f, 0.f, 0.f, 0.f};

    auto stage = [&](short (*Asb)[64], short (*Wsb)[64], int k0) {
#pragma unroll
        for (int r = 0; r < 2; r++) {
            int rowA = r * 32 + w * 8 + srow;
            gl16(&A[(size_t)(m0 + rowA) * CCH + k0 + sg * 8], &Asb[r * 32 + w * 8][0]);
            gl16(&W[(size_t)(o0 + rowA) * CCH + k0 + sg * 8], &Wsb[r * 32 + w * 8][0]);
        }
    };
    auto compute = [&](short (*Asb)[64], short (*Wsb)[64]) {
#pragma unroll
        for (int half = 0; half < 2; half++) {
            bf16x8 af[2], wf[2];
#pragma unroll
            for (int mi = 0; mi < 2; mi++) {
                int row = wm + mi * 16 + fr;
                af[mi] = *(const bf16x8*)&Asb[row][(((half << 2) | fq) ^ (row & 7)) * 8];
            }
#pragma unroll
            for (int ni = 0; ni < 2; ni++) {
                int row = wn + ni * 16 + fr;
                wf[ni] = *(const bf16x8*)&Wsb[row][(((half << 2) | fq) ^ (row & 7)) * 8];
            }
#pragma unroll
            for (int mi = 0; mi < 2; mi++)
#pragma unroll
                for (int ni = 0; ni < 2; ni++)
                    acc[mi][ni] = __builtin_amdgcn_mfma_f32_16x16x32_bf16(
                        af[mi], wf[ni], acc[mi][ni], 0, 0, 0);
        }
    };

    stage(As0, Ws0, 0);
    __syncthreads();
    stage(As1, Ws1, 64);
    compute(As0, Ws0);
    __syncthreads();
    stage(As0, Ws0, 128);
    compute(As1, Ws1);
    __syncthreads();
    stage(As1, Ws1, 192);
    compute(As0, Ws0);
    __syncthreads();
    compute(As1, Ws1);

#pragma unroll
    for (int mi = 0; mi < 2; mi++)
#pragma unroll
        for (int ni = 0; ni < 2; ni++) {
            int o = o0 + wn + ni * 16 + fr;
            int mbase = m0 + wm + mi * 16 + fq * 4;
            if (o < 256) {
#pragma unroll
                for (int r = 0; r < 4; r++)
                    kvk[(size_t)(mbase + r) * 256 + o] = f2bf(acc[mi][ni][r]);
            } else {
                int h = (o - 256) >> 5, d = (o - 256) & 31;
                int b = mbase >> 10, y0 = mbase & 1023;
                size_t rowbase = ((size_t)((b * NH + h) * HD) + d) * NKV + (y0 >> 6) * 64;
                int y4 = y0 & 63;
#pragma unroll
                for (int r = 0; r < 4; r++) {
                    int y64 = y4 + r;
                    int s = (y64 & 15) * 4 + (y64 >> 4);
                    vt[rowbase + s] = f2bf(acc[mi][ni][r]);
                }
            }
        }
}

// ---------------- MFMA flash attention: 64 q rows/block, pi-permuted P, 4 blocks/CU ----------------
__global__ __launch_bounds__(256, 4) void attn_mfma(const short* __restrict__ qb,
                                                    const short* __restrict__ kvk,
                                                    const short* __restrict__ vt,
                                                    short* __restrict__ o) {
    int blk = blockIdx.x;
    int qt = blk & 63; int hh = (blk >> 6) & 7; int b = blk >> 9;
    int t = threadIdx.x; int w = t >> 6; int lane = t & 63;
    int fr = lane & 15, fq = lane >> 4;
    __shared__ short Ks0[128][32], Ks1[128][32];   // 8 KB each
    __shared__ short Vt0[64][64],  Vt1[64][64];    // 8 KB each (permuted kv positions)
    __shared__ short Ps[4][16][64];                // 8 KB, per-wave, permuted
    int n0 = qt * 64 + w * 16;
    bf16x8 qa = *(const bf16x8*)&qb[((size_t)(b * NN) + n0 + fr) * CCH + hh * HD + fq * 8];
    f32x4 oacc[2];
    float lst[4] = {0.f, 0.f, 0.f, 0.f};
#pragma unroll
    for (int nd = 0; nd < 2; nd++) oacc[nd] = f32x4{0.f, 0.f, 0.f, 0.f};

    int srowK = lane >> 2;                    // 0..15 (64B rows)
    int sgK   = (lane & 3) ^ (srowK & 3);
    int srowV = lane >> 3;                    // 0..7 (128B rows)
    int sgV   = (lane & 7) ^ srowV;

    auto stageKV = [&](short (*Ksb)[32], short (*Vtb)[64], int y0) {
#pragma unroll
        for (int r2 = 0; r2 < 2; r2++) {
            int rowK = r2 * 64 + w * 16 + srowK;
            gl16(&kvk[((size_t)(b * NKV) + y0 + rowK) * 256 + hh * HD + sgK * 8],
                 &Ksb[r2 * 64 + w * 16][0]);
        }
#pragma unroll
        for (int r3 = 0; r3 < 2; r3++) {
            int d = w * 8 + srowV;
            gl16(&vt[((size_t)((b * NH + hh) * HD) + d) * NKV + y0 + r3 * 64 + sgV * 8],
                 &Vtb[r3 * 32 + w * 8][0]);
        }
    };
    auto tile = [&](short (*Ksb)[32], short (*Vtb)[64]) {
#pragma unroll
        for (int h2 = 0; h2 < 2; h2++) {
            f32x4 s[4];
            __builtin_amdgcn_s_setprio(1);
#pragma unroll
            for (int ni = 0; ni < 4; ni++) {
                int rowk = h2 * 64 + ni * 16 + fr;
                bf16x8 kb = *(const bf16x8*)&Ksb[rowk][(fq ^ (fr & 3)) * 8];
                s[ni] = __builtin_amdgcn_mfma_f32_16x16x32_bf16(
                    qa, kb, f32x4{0.f, 0.f, 0.f, 0.f}, 0, 0, 0);
            }
            __builtin_amdgcn_s_setprio(0);
            // P: exp, pack 4 bf16, single b64 store at permuted position
            // s(col)=(col&15)*4+(col>>4): lane's cols {i*16+fr} -> slots fr*4+i
#pragma unroll
            for (int r = 0; r < 4; r++) {
                int row = fq * 4 + r;
                float p0 = __expf(fminf(s[0][r], 30.f));
                float p1 = __expf(fminf(s[1][r], 30.f));
                float p2 = __expf(fminf(s[2][r], 30.f));
                float p3 = __expf(fminf(s[3][r], 30.f));
                lst[r] += (p0 + p1) + (p2 + p3);
                unsigned int w0 = cvtpk_bf16(p0, p1);
                unsigned int w1 = cvtpk_bf16(p2, p3);
                int gp = (fr >> 1) ^ (row & 7);     // 16B-group swizzle
                *(uint2*)&Ps[w][row][gp * 8 + (fr & 1) * 4] = make_uint2(w0, w1);
            }
            __builtin_amdgcn_s_setprio(1);
#pragma unroll
            for (int ks = 0; ks < 2; ks++) {
                int gk = ks * 4 + fq;               // slot group 0..7
                bf16x8 pa = *(const bf16x8*)&Ps[w][fr][(gk ^ (fr & 7)) * 8];
#pragma unroll
                for (int nd = 0; nd < 2; nd++) {
                    int rowv = nd * 16 + fr;
                    bf16x8 vb = *(const bf16x8*)&Vtb[h2 * 32 + rowv][(gk ^ (rowv & 7)) * 8];
                    oacc[nd] = __builtin_amdgcn_mfma_f32_16x16x32_bf16(
                        pa, vb, oacc[nd], 0, 0, 0);
                }
            }
            __builtin_amdgcn_s_setprio(0);
        }
    };

    stageKV(Ks0, Vt0, 0);
    __syncthreads();
    for (int y0 = 0; y0 < NKV; y0 += 256) {
        if (y0 + 128 < NKV) stageKV(Ks1, Vt1, y0 + 128);   // issue early
        tile(Ks0, Vt0);
        __syncthreads();                                   // wait late
        if (y0 + 256 < NKV) stageKV(Ks0, Vt0, y0 + 256);
        tile(Ks1, Vt1);
        __syncthreads();
    }
#pragma unroll
    for (int r = 0; r < 4; r++) {
        float ls = lst[r];
#pragma unroll
        for (int off = 1; off < 16; off <<= 1)
            ls += __shfl_xor(ls, off);
        float inv = 1.f / ls;
        int row = n0 + fq * 4 + r;
#pragma unroll
        for (int nd = 0; nd < 2; nd++)
            o[((size_t)(b * NN) + row) * CCH + hh * HD + nd * 16 + fr] =
                f2bf(oacc[nd][r] * inv);
    }
}

// ---------------- depthwise 3x3 + bias + tanh-GELU, bf16 in/out ----------------
__global__ __launch_bounds__(256, 2) void dwconv_gelu(const short* __restrict__ xf,
                                                      const float* __restrict__ pe_w,
                                                      const float* __restrict__ pe_b,
                                                      short* __restrict__ out) {
    int blk = blockIdx.x;
    int cg = blk & 15, sp = (blk >> 4) & 15, b = blk >> 8;
    int r0 = (sp >> 2) * 16, c0 = (sp & 3) * 16;
    int ch0 = cg * 64;
    int t = threadIdx.x;
    __shared__ short tile[18][18][64];
    for (int idx = t; idx < 18 * 18 * 8; idx += 256) {
        int pix = idx >> 3, part = idx & 7;
        int row = pix / 18, col = pix - row * 18;
        int gr = r0 + row - 1, gc = c0 + col - 1;
        bf16x8 v = {0, 0, 0, 0, 0, 0, 0, 0};
        if (gr >= 0 && gr < 64 && gc >= 0 && gc < 64)
            v = *(const bf16x8*)&xf[((size_t)(b * NN) + gr * GW + gc) * HIDN + ch0 + part * 8];
        *(bf16x8*)&tile[row][col][part * 8] = v;
    }
    __syncthreads();
    int cl = t & 63, sg = t >> 6;
    int ch = ch0 + cl;
    float wv[9];
#pragma unroll
    for (int k = 0; k < 9; k++) wv[k] = pe_w[ch * 9 + k];
    float bias = pe_b[ch];
#pragma unroll
    for (int q = 0; q < 4; q++) {
        int lr = sg * 4 + q;
        float cA[3], cB[3], cC[3];
#pragma unroll
        for (int ki = 0; ki < 3; ki++) {
            cA[ki] = bf2f(tile[lr + ki][0][cl]);
            cB[ki] = bf2f(tile[lr + ki][1][cl]);
        }
        for (int cc = 0; cc < 16; cc++) {
#pragma unroll
            for (int ki = 0; ki < 3; ki++) cC[ki] = bf2f(tile[lr + ki][cc + 2][cl]);
            float acc = bias;
#pragma unroll
            for (int ki = 0; ki < 3; ki++)
                acc += cA[ki] * wv[ki * 3] + cB[ki] * wv[ki * 3 + 1] + cC[ki] * wv[ki * 3 + 2];
            float z = 0.7978845608f * (acc + 0.044715f * acc * acc * acc);
            float e = __expf(-2.f * fabsf(z));
            float th = (1.f - e) / (1.f + e);
            th = (z < 0.f) ? -th : th;
            float gg = 0.5f * acc * (1.f + th);
            out[((size_t)(b * NN) + (r0 + lr) * GW + c0 + cc) * HIDN + ch] = f2bf(gg);
#pragma unroll
            for (int ki = 0; ki < 3; ki++) { cA[ki] = cB[ki]; cB[ki] = cC[ki]; }
        }
    }
}

extern "C" void kernel_launch(void* const* d_in, const int* in_sizes, int n_in,
                              void* d_out, int out_size, void* d_ws, size_t ws_size,
                              hipStream_t stream) {
    const float* x      = (const float*)d_in[0];
    const float* ln1_g  = (const float*)d_in[3];
    const float* ln1_b  = (const float*)d_in[4];
    const float* q_w    = (const float*)d_in[5];
    const float* kv_w   = (const float*)d_in[6];
    const float* sr_w   = (const float*)d_in[7];
    const float* sr_b   = (const float*)d_in[8];
    const float* srn_g  = (const float*)d_in[9];
    const float* srn_b  = (const float*)d_in[10];
    const float* proj_w = (const float*)d_in[11];
    const float* proj_b = (const float*)d_in[12];
    const float* ln2_g  = (const float*)d_in[13];
    const float* ln2_b  = (const float*)d_in[14];
    const float* fc1_w  = (const float*)d_in[15];
    const float* fc1_b  = (const float*)d_in[16];
    const float* pe_w   = (const float*)d_in[17];
    const float* pe_b   = (const float*)d_in[18];
    const float* fc2_w  = (const float*)d_in[19];
    const float* fc2_b  = (const float*)d_in[20];
    float* out = (float*)d_out;

    // workspace carve (bytes)
    char* base = (char*)d_ws;
    short* xn    = (short*)(base);                   // [0,4M)   xn / xn2 bf16
    short* qb    = (short*)(base + (4ull  << 20));   // [4,8)    q bf16 (pre-scaled)
    short* xbf   = (short*)(base + (8ull  << 20));   // [8,12)   x bf16 (residual copy)
    float* srtmp = (float*)(base + (12ull << 20));   // [12,14)  sr conv out f32 [2048][256]
    short* xkvn  = (short*)(base + (14ull << 20));   // [14,15)  x_kvn bf16
    short* kvk   = (short*)(base + (15ull << 20));   // [15,16)  k bf16 [2048][256]
    short* vtb   = (short*)(base + (17ull << 20));   // [17,18)  V^T bf16 [512][1024] (permuted)
    short* obf   = (short*)(base + (18ull << 20));   // [18,22)  attn out bf16
    short* x1    = (short*)(base + (22ull << 20));   // [22,26)  x1 bf16
    short* xf1   = (short*)(base + (30ull << 20));   // [30,46)  fc1 out bf16 [8192][1024]
    short* xf2g  = (short*)(base + (46ull << 20));   // [46,62)  gelu(dwconv) bf16
    short* qwb   = (short*)(base + (62ull << 20));   // weights bf16
    short* kvwb  = qwb  + 65536;
    short* pjwb  = kvwb + 131072;
    short* f1wb  = pjwb + 65536;
    short* f2wb  = f1wb + 262144;
    short* srwb  = f2wb + 262144;

    // 0. weights -> bf16 (sr reordered) + x->bf16 + LN1 (wave), one launch
    prep_kernel<<<4096 + 2048 + BB * NN / 4, 256, 0, stream>>>(
        q_w, kv_w, proj_w, fc1_w, fc2_w, sr_w,
        qwb, kvwb, pjwb, f1wb, f2wb, srwb,
        x, ln1_g, ln1_b, xn, xbf);
    // 2+3. q-GEMM and sr-GEMM merged
    qsr_gemm<<<768, 256, 0, stream>>>(xn, qwb, qb, srwb, sr_b, srtmp);
    // 3c. x_kvn = LN(srtmp)
    ln_wave<false><<<BB * NKV / 4, 256, 0, stream>>>(srtmp, srn_g, srn_b, xkvn);
    // 4. kv = x_kvn . kv_w^T -> kvk (k half) + vtb (v half, transposed+permuted)
    {
        dim3 g(512 / 64, (BB * NKV) / 64);
        kv_gemm<<<g, 256, 0, stream>>>(xkvn, kvwb, kvk, vtb);
    }
    // 5. attention -> obf (64 q rows/block, 4 blocks/CU)
    attn_mfma<<<BB * NH * (NN / 64), 256, 0, stream>>>(qb, kvk, vtb, obf);
    // 6. x1 = x + obf . proj_w^T + proj_b  (bf16 residual, bf16 out)
    {
        dim3 g(CCH / 64, (BB * NN) / 64);
        gemm64<true, 2><<<g, 256, 0, stream>>>(obf, pjwb, proj_b, xbf, x1, BB * NN, CCH, CCH);
    }
    // 7. xn2 = LN2(x1) (bf16 in, reuse xn)
    ln_wave<true><<<BB * NN / 4, 256, 0, stream>>>(x1, ln2_g, ln2_b, xn);
    // 8. xf1 = xn2 . fc1_w^T + fc1_b  (bf16 out, 128x128 tile)
    {
        dim3 g(HIDN / 128, (BB * NN) / 128);
        gemm_fc1<<<g, 256, 0, stream>>>(xn, f1wb, fc1_b, xf1, BB * NN, HIDN, CCH);
    }
    // 9. xf2g = gelu(dwconv3x3(xf1) + pe_b)
    dwconv_gelu<<<BB * 256, 256, 0, stream>>>(xf1, pe_w, pe_b, xf2g);
    // 10. out = x1 + xf2g . fc2_w^T + fc2_b  (f32)
    {
        dim3 g(CCH / 64, (BB * NN) / 64);
        gemm64<false, 2><<<g, 256, 0, stream>>>(xf2g, f2wb, fc2_b, x1, out, BB * NN, CCH, HIDN);
    }
}

// Round 18
// 109.583 us; speedup vs baseline: 1.1066x; 1.0100x over previous
//
#include <hip/hip_runtime.h>
#include <math.h>

// problem constants
constexpr int BB   = 2;
constexpr int NN   = 4096;
constexpr int CCH  = 256;   // channels
constexpr int NH   = 8;     // heads
constexpr int HD   = 32;    // head dim
constexpr int GW   = 64;    // spatial h = w
constexpr int NKV  = 1024;  // (64/2)*(64/2)
constexpr int HIDN = 1024;
constexpr float EPSF = 1e-5f;

typedef short  bf16x8 __attribute__((ext_vector_type(8)));
typedef short  bf16x4 __attribute__((ext_vector_type(4)));
typedef float  f32x4  __attribute__((ext_vector_type(4)));

__device__ __forceinline__ short f2bf(float f) {
    unsigned int u = __float_as_uint(f);
    unsigned int r = (u + 0x7FFFu + ((u >> 16) & 1u)) >> 16;   // RNE
    return (short)r;
}
__device__ __forceinline__ float bf2f(short s) {
    return __uint_as_float(((unsigned int)(unsigned short)s) << 16);
}
// packed f32x2 -> bf16x2 (RNE), src0 -> low half
__device__ __forceinline__ unsigned int cvtpk_bf16(float a, float b) {
    unsigned int r;
    asm("v_cvt_pk_bf16_f32 %0, %1, %2" : "=v"(r) : "v"(a), "v"(b));
    return r;
}
// async global->LDS, 16B per lane; lds base must be wave-uniform (HW adds lane*16)
__device__ __forceinline__ void gl16(const void* g, void* l) {
    __builtin_amdgcn_global_load_lds(
        (const __attribute__((address_space(1))) void*)g,
        (__attribute__((address_space(3))) void*)l, 16, 0, 0);
}

// ---------------- prep: weight cvt (blocks 0..4095)
//                  + LN1 wave-per-row + x->bf16 (4096..6143; 4 rows/block) ----------------
// sr_w reordered: srwb[o][q*256+c] = sr_w[o][c*4+q]  (K-dim quad-major)
__global__ __launch_bounds__(256) void prep_kernel(const float* __restrict__ q_w,
                                                   const float* __restrict__ kv_w,
                                                   const float* __restrict__ proj_w,
                                                   const float* __restrict__ fc1_w,
                                                   const float* __restrict__ fc2_w,
                                                   const float* __restrict__ sr_w,
                                                   short* qwb, short* kvwb, short* pjwb,
                                                   short* f1wb, short* f2wb, short* srwb,
                                                   const float* __restrict__ x,
                                                   const float* __restrict__ ln1_g,
                                                   const float* __restrict__ ln1_b,
                                                   short* __restrict__ xn,
                                                   short* __restrict__ xbf) {
    int t = threadIdx.x;
    if (blockIdx.x < 4096) {
        int i = blockIdx.x * 256 + t;
        if (i < 65536) { qwb[i] = f2bf(q_w[i] * 0.17677669529663687f); return; }
        i -= 65536;
        if (i < 131072) { kvwb[i] = f2bf(kv_w[i]); return; }
        i -= 131072;
        if (i < 65536) { pjwb[i] = f2bf(proj_w[i]); return; }
        i -= 65536;
        if (i < 262144) { f1wb[i] = f2bf(fc1_w[i]); return; }
        i -= 262144;
        if (i < 262144) { f2wb[i] = f2bf(fc2_w[i]); return; }
        i -= 262144;
        {
            int o = i >> 10, rem = i & 1023, c = rem >> 2, q = rem & 3;
            srwb[o * 1024 + q * 256 + c] = f2bf(sr_w[i]);
        }
        return;
    }
    // LN1 (wave-per-row, 4 rows/block) + x->bf16 copy in the same pass
    int w = t >> 6, lane = t & 63;
    int row = (blockIdx.x - 4096) * 4 + w;
    float4 fv = *(const float4*)&x[(size_t)row * CCH + lane * 4];
    float v[4] = {fv.x, fv.y, fv.z, fv.w};
    bf16x4 xv;
#pragma unroll
    for (int j = 0; j < 4; j++) xv[j] = f2bf(v[j]);
    *(bf16x4*)&xbf[(size_t)row * CCH + lane * 4] = xv;
    float a = v[0] + v[1] + v[2] + v[3];
    float b = v[0]*v[0] + v[1]*v[1] + v[2]*v[2] + v[3]*v[3];
#pragma unroll
    for (int off = 1; off < 64; off <<= 1) {
        a += __shfl_xor(a, off);
        b += __shfl_xor(b, off);
    }
    float mu = a * (1.0f / CCH);
    float var = b * (1.0f / CCH) - mu * mu;
    float rs = rsqrtf(var + EPSF);
    bf16x4 ov;
#pragma unroll
    for (int j = 0; j < 4; j++)
        ov[j] = f2bf((v[j] - mu) * rs * ln1_g[lane * 4 + j] + ln1_b[lane * 4 + j]);
    *(bf16x4*)&xn[(size_t)row * CCH + lane * 4] = ov;
}

// ---------------- wave-per-row LayerNorm (C=256): 4 rows/block, no barriers ----------------
template <bool INBF>
__global__ __launch_bounds__(256) void ln_wave(const void* __restrict__ in,
                                               const float* __restrict__ g,
                                               const float* __restrict__ bta,
                                               short* __restrict__ out) {
    int t = threadIdx.x;
    int w = t >> 6, lane = t & 63;
    int row = blockIdx.x * 4 + w;
    float v[4];
    if (INBF) {
        bf16x4 bv = *(const bf16x4*)&((const short*)in)[(size_t)row * CCH + lane * 4];
#pragma unroll
        for (int j = 0; j < 4; j++) v[j] = bf2f(bv[j]);
    } else {
        float4 fv = *(const float4*)&((const float*)in)[(size_t)row * CCH + lane * 4];
        v[0] = fv.x; v[1] = fv.y; v[2] = fv.z; v[3] = fv.w;
    }
    float a = v[0] + v[1] + v[2] + v[3];
    float b = v[0]*v[0] + v[1]*v[1] + v[2]*v[2] + v[3]*v[3];
#pragma unroll
    for (int off = 1; off < 64; off <<= 1) {
        a += __shfl_xor(a, off);
        b += __shfl_xor(b, off);
    }
    float mu = a * (1.0f / CCH);
    float var = b * (1.0f / CCH) - mu * mu;
    float rs = rsqrtf(var + EPSF);
    bf16x4 ov;
#pragma unroll
    for (int j = 0; j < 4; j++)
        ov[j] = f2bf((v[j] - mu) * rs * g[lane * 4 + j] + bta[lane * 4 + j]);
    *(bf16x4*)&out[(size_t)row * CCH + lane * 4] = ov;
}

// ---------------- gemm64 body (device fn): 64x64 tile, BK=64, 2-phase dbuf ----------------
template <bool OUTB, int RESMODE>
__device__ __forceinline__ void gemm64_body(const short* __restrict__ A,
                                            const short* __restrict__ W,
                                            const float* __restrict__ bias,
                                            const void* __restrict__ res,
                                            void* __restrict__ outp,
                                            int M, int O, int K, int bx, int by,
                                            short (*As0)[64], short (*Ws0)[64],
                                            short (*As1)[64], short (*Ws1)[64]) {
    int t = threadIdx.x;
    int m0 = by * 64, o0 = bx * 64;
    int w = t >> 6, lane = t & 63;
    int wm = (w >> 1) * 32, wn = (w & 1) * 32;
    int fr = lane & 15, fq = lane >> 4;
    int srow = lane >> 3;
    int sg   = (lane & 7) ^ srow;
    f32x4 acc[2][2];
#pragma unroll
    for (int mi = 0; mi < 2; mi++)
#pragma unroll
        for (int ni = 0; ni < 2; ni++)
            acc[mi][ni] = f32x4{0.f, 0.f, 0.f, 0.f};

    auto stage = [&](short (*Asb)[64], short (*Wsb)[64], int k0) {
#pragma unroll
        for (int r = 0; r < 2; r++) {
            int rowA = r * 32 + w * 8 + srow;
            gl16(&A[(size_t)(m0 + rowA) * K + k0 + sg * 8], &Asb[r * 32 + w * 8][0]);
            gl16(&W[(size_t)(o0 + rowA) * K + k0 + sg * 8], &Wsb[r * 32 + w * 8][0]);
        }
    };
    auto compute = [&](short (*Asb)[64], short (*Wsb)[64]) {
#pragma unroll
        for (int half = 0; half < 2; half++) {
            bf16x8 af[2], wf[2];
#pragma unroll
            for (int mi = 0; mi < 2; mi++) {
                int row = wm + mi * 16 + fr;
                af[mi] = *(const bf16x8*)&Asb[row][(((half << 2) | fq) ^ (row & 7)) * 8];
            }
#pragma unroll
            for (int ni = 0; ni < 2; ni++) {
                int row = wn + ni * 16 + fr;
                wf[ni] = *(const bf16x8*)&Wsb[row][(((half << 2) | fq) ^ (row & 7)) * 8];
            }
#pragma unroll
            for (int mi = 0; mi < 2; mi++)
#pragma unroll
                for (int ni = 0; ni < 2; ni++)
                    acc[mi][ni] = __builtin_amdgcn_mfma_f32_16x16x32_bf16(
                        af[mi], wf[ni], acc[mi][ni], 0, 0, 0);
        }
    };

    stage(As0, Ws0, 0);
    __syncthreads();
    for (int k0 = 0; k0 < K; k0 += 128) {
        if (k0 + 64 < K) stage(As1, Ws1, k0 + 64);
        compute(As0, Ws0);
        __syncthreads();
        if (k0 + 128 < K) stage(As0, Ws0, k0 + 128);
        if (k0 + 64 < K) compute(As1, Ws1);
        __syncthreads();
    }
#pragma unroll
    for (int mi = 0; mi < 2; mi++)
#pragma unroll
        for (int ni = 0; ni < 2; ni++)
#pragma unroll
            for (int r = 0; r < 4; r++) {
                int m = m0 + wm + mi * 16 + fq * 4 + r;
                int o = o0 + wn + ni * 16 + fr;
                float v = acc[mi][ni][r];
                if (bias) v += bias[o];
                if (RESMODE == 1) v += ((const float*)res)[(size_t)m * O + o];
                if (RESMODE == 2) v += bf2f(((const short*)res)[(size_t)m * O + o]);
                if (OUTB) ((short*)outp)[(size_t)m * O + o] = f2bf(v);
                else      ((float*)outp)[(size_t)m * O + o] = v;
            }
}

// standalone gemm64 kernel (proj, fc2)
template <bool OUTB, int RESMODE>
__global__ __launch_bounds__(256, 4) void gemm64(const short* __restrict__ A,
                                                 const short* __restrict__ W,
                                                 const float* __restrict__ bias,
                                                 const void* __restrict__ res,
                                                 void* __restrict__ outp,
                                                 int M, int O, int K) {
    __shared__ short As0[64][64], Ws0[64][64];
    __shared__ short As1[64][64], Ws1[64][64];
    gemm64_body<OUTB, RESMODE>(A, W, bias, res, outp, M, O, K,
                               blockIdx.x, blockIdx.y, As0, Ws0, As1, Ws1);
}

// ---------------- SR conv body: fused im2col gather (K reordered: k = q*256+c) ----------------
__device__ __forceinline__ void sr_body(const short* __restrict__ xn,
                                        const short* __restrict__ Wsr,
                                        const float* __restrict__ sr_b,
                                        float* __restrict__ srtmp, int bx, int by,
                                        short (*As0)[64], short (*As1)[64],
                                        short (*Ws0)[64], short (*Ws1)[64]) {
    int t = threadIdx.x;
    int m0 = by * 32, o0 = bx * 64;
    int w = t >> 6, lane = t & 63;
    int wm = (w >> 1) * 16, wn = (w & 1) * 32;
    int fr = lane & 15, fq = lane >> 4;
    int srow = lane >> 3;
    int sg   = (lane & 7) ^ srow;
    int arow = w * 8 + srow;
    int p = m0 + arow;
    int b = p >> 10, pp = p & 1023, ii = pp >> 5, jj = pp & 31;
    int nbase = ii * 128 + jj * 2;
    size_t xbase = (size_t)(b * NN) * CCH;
    f32x4 acc[2];
    acc[0] = f32x4{0.f, 0.f, 0.f, 0.f};
    acc[1] = f32x4{0.f, 0.f, 0.f, 0.f};

    auto stage = [&](short (*Asb)[64], short (*Wsb)[64], int k0) {
        int q = k0 >> 8, c0 = k0 & 255;
        int n = nbase + (q >> 1) * 64 + (q & 1);
        gl16(&xn[xbase + (size_t)n * CCH + c0 + sg * 8], &Asb[w * 8][0]);
#pragma unroll
        for (int r = 0; r < 2; r++)
            gl16(&Wsr[(size_t)(o0 + r * 32 + w * 8 + srow) * 1024 + k0 + sg * 8],
                 &Wsb[r * 32 + w * 8][0]);
    };
    auto compute = [&](short (*Asb)[64], short (*Wsb)[64]) {
#pragma unroll
        for (int half = 0; half < 2; half++) {
            int cg = (half << 2) | fq;
            int rowa = wm + fr;
            bf16x8 af = *(const bf16x8*)&Asb[rowa][(cg ^ (rowa & 7)) * 8];
            bf16x8 wf[2];
#pragma unroll
            for (int ni = 0; ni < 2; ni++) {
                int row = wn + ni * 16 + fr;
                wf[ni] = *(const bf16x8*)&Wsb[row][(cg ^ (row & 7)) * 8];
            }
#pragma unroll
            for (int ni = 0; ni < 2; ni++)
                acc[ni] = __builtin_amdgcn_mfma_f32_16x16x32_bf16(
                    af, wf[ni], acc[ni], 0, 0, 0);
        }
    };

    stage(As0, Ws0, 0);
    __syncthreads();
    for (int k0 = 0; k0 < 1024; k0 += 128) {
        if (k0 + 64 < 1024) stage(As1, Ws1, k0 + 64);
        compute(As0, Ws0);
        __syncthreads();
        if (k0 + 128 < 1024) stage(As0, Ws0, k0 + 128);
        compute(As1, Ws1);
        __syncthreads();
    }
#pragma unroll
    for (int ni = 0; ni < 2; ni++)
#pragma unroll
        for (int r = 0; r < 4; r++) {
            int m = m0 + wm + fq * 4 + r;
            int o = o0 + wn + ni * 16 + fr;
            srtmp[(size_t)m * CCH + o] = acc[ni][r] + sr_b[o];
        }
}

// ---------------- merged q-GEMM (blocks 0..511) + sr-GEMM (blocks 512..767) ----------------
__global__ __launch_bounds__(256, 4) void qsr_gemm(const short* __restrict__ xn,
                                                   const short* __restrict__ qwb,
                                                   short* __restrict__ qb,
                                                   const short* __restrict__ srwb,
                                                   const float* __restrict__ sr_b,
                                                   float* __restrict__ srtmp) {
    __shared__ short pool[16384];   // 32 KB
    int i = blockIdx.x;
    if (i < 512) {
        gemm64_body<true, 0>(xn, qwb, nullptr, nullptr, qb, BB * NN, CCH, CCH,
                             i & 3, i >> 2,
                             (short(*)[64])(pool),
                             (short(*)[64])(pool + 4096),
                             (short(*)[64])(pool + 8192),
                             (short(*)[64])(pool + 12288));
    } else {
        i -= 512;
        sr_body(xn, srwb, sr_b, srtmp, i & 3, i >> 2,
                (short(*)[64])(pool),
                (short(*)[64])(pool + 2048),
                (short(*)[64])(pool + 4096),
                (short(*)[64])(pool + 8192));
    }
}

// ---------------- fc1 GEMM, 128x128 tile, BK=64, dbuf ----------------
__global__ __launch_bounds__(256, 2) void gemm_fc1(const short* __restrict__ A,
                                                   const short* __restrict__ W,
                                                   const float* __restrict__ bias,
                                                   short* __restrict__ outp,
                                                   int M, int O, int K) {
    __shared__ short As0[128][64], Ws0[128][64];
    __shared__ short As1[128][64], Ws1[128][64];
    int t = threadIdx.x;
    int m0 = blockIdx.y * 128, o0 = blockIdx.x * 128;
    int w = t >> 6, lane = t & 63;
    int wm = (w >> 1) * 64, wn = (w & 1) * 64;
    int fr = lane & 15, fq = lane >> 4;
    int srow = lane >> 3;
    int sg   = (lane & 7) ^ srow;
    f32x4 acc[4][4];
#pragma unroll
    for (int mi = 0; mi < 4; mi++)
#pragma unroll
        for (int ni = 0; ni < 4; ni++)
            acc[mi][ni] = f32x4{0.f, 0.f, 0.f, 0.f};

    auto stage = [&](short (*Asb)[64], short (*Wsb)[64], int k0) {
#pragma unroll
        for (int r = 0; r < 4; r++) {
            int rowA = r * 32 + w * 8 + srow;
            gl16(&A[(size_t)(m0 + rowA) * K + k0 + sg * 8], &Asb[r * 32 + w * 8][0]);
            gl16(&W[(size_t)(o0 + rowA) * K + k0 + sg * 8], &Wsb[r * 32 + w * 8][0]);
        }
    };
    auto compute = [&](short (*Asb)[64], short (*Wsb)[64]) {
#pragma unroll
        for (int half = 0; half < 2; half++) {
            bf16x8 af[4], wf[4];
#pragma unroll
            for (int mi = 0; mi < 4; mi++) {
                int row = wm + mi * 16 + fr;
                af[mi] = *(const bf16x8*)&Asb[row][(((half << 2) | fq) ^ (row & 7)) * 8];
            }
#pragma unroll
            for (int ni = 0; ni < 4; ni++) {
                int row = wn + ni * 16 + fr;
                wf[ni] = *(const bf16x8*)&Wsb[row][(((half << 2) | fq) ^ (row & 7)) * 8];
            }
#pragma unroll
            for (int mi = 0; mi < 4; mi++)
#pragma unroll
                for (int ni = 0; ni < 4; ni++)
                    acc[mi][ni] = __builtin_amdgcn_mfma_f32_16x16x32_bf16(
                        af[mi], wf[ni], acc[mi][ni], 0, 0, 0);
        }
    };

    stage(As0, Ws0, 0);
    __syncthreads();
    for (int k0 = 0; k0 < K; k0 += 128) {
        if (k0 + 64 < K) stage(As1, Ws1, k0 + 64);
        compute(As0, Ws0);
        __syncthreads();
        if (k0 + 128 < K) stage(As0, Ws0, k0 + 128);
        if (k0 + 64 < K) compute(As1, Ws1);
        __syncthreads();
    }
#pragma unroll
    for (int mi = 0; mi < 4; mi++)
#pragma unroll
        for (int ni = 0; ni < 4; ni++)
#pragma unroll
            for (int r = 0; r < 4; r++) {
                int m = m0 + wm + mi * 16 + fq * 4 + r;
                int o = o0 + wn + ni * 16 + fr;
                outp[(size_t)m * O + o] = f2bf(acc[mi][ni][r] + bias[o]);
            }
}

// ---------------- kv GEMM with fused V-transpose epilogue ----------------
// o<256 -> kvk[m][o] bf16; o>=256 -> vt permuted: within each 64-kv block,
// kv y stored at s=(y&15)*4+(y>>4).
__global__ __launch_bounds__(256, 4) void kv_gemm(const short* __restrict__ A,
                                                  const short* __restrict__ W,
                                                  short* __restrict__ kvk,
                                                  short* __restrict__ vt) {
    __shared__ short As0[64][64], Ws0[64][64];
    __shared__ short As1[64][64], Ws1[64][64];
    int t = threadIdx.x;
    int m0 = blockIdx.y * 64, o0 = blockIdx.x * 64;
    int w = t >> 6, lane = t & 63;
    int wm = (w >> 1) * 32, wn = (w & 1) * 32;
    int fr = lane & 15, fq = lane >> 4;
    int srow = lane >> 3;
    int sg   = (lane & 7) ^ srow;
    f32x4 acc[2][2];
#pragma unroll
    for (int mi = 0; mi < 2; mi++)
#pragma unroll
        for (int ni = 0; ni < 2; ni++)
            acc[mi][ni] = f32x4{0.f, 0.f, 0.f, 0.f};

    auto stage = [&](short (*Asb)[64], short (*Wsb)[64], int k0) {
#pragma unroll
        for (int r = 0; r < 2; r++) {
            int rowA = r * 32 + w * 8 + srow;
            gl16(&A[(size_t)(m0 + rowA) * CCH + k0 + sg * 8], &Asb[r * 32 + w * 8][0]);
            gl16(&W[(size_t)(o0 + rowA) * CCH + k0 + sg * 8], &Wsb[r * 32 + w * 8][0]);
        }
    };
    auto compute = [&](short (*Asb)[64], short (*Wsb)[64]) {
#pragma unroll
        for (int half = 0; half < 2; half++) {
            bf16x8 af[2], wf[2];
#pragma unroll
            for (int mi = 0; mi < 2; mi++) {
                int row = wm + mi * 16 + fr;
                af[mi] = *(const bf16x8*)&Asb[row][(((half << 2) | fq) ^ (row & 7)) * 8];
            }
#pragma unroll
            for (int ni = 0; ni < 2; ni++) {
                int row = wn + ni * 16 + fr;
                wf[ni] = *(const bf16x8*)&Wsb[row][(((half << 2) | fq) ^ (row & 7)) * 8];
            }
#pragma unroll
            for (int mi = 0; mi < 2; mi++)
#pragma unroll
                for (int ni = 0; ni < 2; ni++)
                    acc[mi][ni] = __builtin_amdgcn_mfma_f32_16x16x32_bf16(
                        af[mi], wf[ni], acc[mi][ni], 0, 0, 0);
        }
    };

    stage(As0, Ws0, 0);
    __syncthreads();
    stage(As1, Ws1, 64);
    compute(As0, Ws0);
    __syncthreads();
    stage(As0, Ws0, 128);
    compute(As1, Ws1);
    __syncthreads();
    stage(As1, Ws1, 192);
    compute(As0, Ws0);
    __syncthreads();
    compute(As1, Ws1);

#pragma unroll
    for (int mi = 0; mi < 2; mi++)
#pragma unroll
        for (int ni = 0; ni < 2; ni++) {
            int o = o0 + wn + ni * 16 + fr;
            int mbase = m0 + wm + mi * 16 + fq * 4;
            if (o < 256) {
#pragma unroll
                for (int r = 0; r < 4; r++)
                    kvk[(size_t)(mbase + r) * 256 + o] = f2bf(acc[mi][ni][r]);
            } else {
                int h = (o - 256) >> 5, d = (o - 256) & 31;
                int b = mbase >> 10, y0 = mbase & 1023;
                size_t rowbase = ((size_t)((b * NH + h) * HD) + d) * NKV + (y0 >> 6) * 64;
                int y4 = y0 & 63;
#pragma unroll
                for (int r = 0; r < 4; r++) {
                    int y64 = y4 + r;
                    int s = (y64 & 15) * 4 + (y64 >> 4);
                    vt[rowbase + s] = f2bf(acc[mi][ni][r]);
                }
            }
        }
}

// ---------------- MFMA flash attention: 64 q rows/block, pi-permuted P, 4 blocks/CU ----------------
__global__ __launch_bounds__(256, 4) void attn_mfma(const short* __restrict__ qb,
                                                    const short* __restrict__ kvk,
                                                    const short* __restrict__ vt,
                                                    short* __restrict__ o) {
    int blk = blockIdx.x;
    int qt = blk & 63; int hh = (blk >> 6) & 7; int b = blk >> 9;
    int t = threadIdx.x; int w = t >> 6; int lane = t & 63;
    int fr = lane & 15, fq = lane >> 4;
    __shared__ short Ks0[128][32], Ks1[128][32];   // 8 KB each
    __shared__ short Vt0[64][64],  Vt1[64][64];    // 8 KB each (permuted kv positions)
    __shared__ short Ps[4][16][64];                // 8 KB, per-wave, permuted
    int n0 = qt * 64 + w * 16;
    bf16x8 qa = *(const bf16x8*)&qb[((size_t)(b * NN) + n0 + fr) * CCH + hh * HD + fq * 8];
    f32x4 oacc[2];
    float lst[4] = {0.f, 0.f, 0.f, 0.f};
#pragma unroll
    for (int nd = 0; nd < 2; nd++) oacc[nd] = f32x4{0.f, 0.f, 0.f, 0.f};

    int srowK = lane >> 2;                    // 0..15 (64B rows)
    int sgK   = (lane & 3) ^ (srowK & 3);
    int srowV = lane >> 3;                    // 0..7 (128B rows)
    int sgV   = (lane & 7) ^ srowV;

    auto stageKV = [&](short (*Ksb)[32], short (*Vtb)[64], int y0) {
#pragma unroll
        for (int r2 = 0; r2 < 2; r2++) {
            int rowK = r2 * 64 + w * 16 + srowK;
            gl16(&kvk[((size_t)(b * NKV) + y0 + rowK) * 256 + hh * HD + sgK * 8],
                 &Ksb[r2 * 64 + w * 16][0]);
        }
#pragma unroll
        for (int r3 = 0; r3 < 2; r3++) {
            int d = w * 8 + srowV;
            gl16(&vt[((size_t)((b * NH + hh) * HD) + d) * NKV + y0 + r3 * 64 + sgV * 8],
                 &Vtb[r3 * 32 + w * 8][0]);
        }
    };
    auto tile = [&](short (*Ksb)[32], short (*Vtb)[64]) {
#pragma unroll
        for (int h2 = 0; h2 < 2; h2++) {
            f32x4 s[4];
            __builtin_amdgcn_s_setprio(1);
#pragma unroll
            for (int ni = 0; ni < 4; ni++) {
                int rowk = h2 * 64 + ni * 16 + fr;
                bf16x8 kb = *(const bf16x8*)&Ksb[rowk][(fq ^ (fr & 3)) * 8];
                s[ni] = __builtin_amdgcn_mfma_f32_16x16x32_bf16(
                    qa, kb, f32x4{0.f, 0.f, 0.f, 0.f}, 0, 0, 0);
            }
            __builtin_amdgcn_s_setprio(0);
            // P: exp, pack 4 bf16, single b64 store at permuted position
            // s(col)=(col&15)*4+(col>>4): lane's cols {i*16+fr} -> slots fr*4+i
#pragma unroll
            for (int r = 0; r < 4; r++) {
                int row = fq * 4 + r;
                float p0 = __expf(fminf(s[0][r], 30.f));
                float p1 = __expf(fminf(s[1][r], 30.f));
                float p2 = __expf(fminf(s[2][r], 30.f));
                float p3 = __expf(fminf(s[3][r], 30.f));
                lst[r] += (p0 + p1) + (p2 + p3);
                unsigned int w0 = cvtpk_bf16(p0, p1);
                unsigned int w1 = cvtpk_bf16(p2, p3);
                int gp = (fr >> 1) ^ (row & 7);     // 16B-group swizzle
                *(uint2*)&Ps[w][row][gp * 8 + (fr & 1) * 4] = make_uint2(w0, w1);
            }
            __builtin_amdgcn_s_setprio(1);
#pragma unroll
            for (int ks = 0; ks < 2; ks++) {
                int gk = ks * 4 + fq;               // slot group 0..7
                bf16x8 pa = *(const bf16x8*)&Ps[w][fr][(gk ^ (fr & 7)) * 8];
#pragma unroll
                for (int nd = 0; nd < 2; nd++) {
                    int rowv = nd * 16 + fr;
                    bf16x8 vb = *(const bf16x8*)&Vtb[h2 * 32 + rowv][(gk ^ (rowv & 7)) * 8];
                    oacc[nd] = __builtin_amdgcn_mfma_f32_16x16x32_bf16(
                        pa, vb, oacc[nd], 0, 0, 0);
                }
            }
            __builtin_amdgcn_s_setprio(0);
        }
    };

    stageKV(Ks0, Vt0, 0);
    __syncthreads();
    for (int y0 = 0; y0 < NKV; y0 += 256) {
        if (y0 + 128 < NKV) stageKV(Ks1, Vt1, y0 + 128);   // issue early
        tile(Ks0, Vt0);
        __syncthreads();                                   // wait late
        if (y0 + 256 < NKV) stageKV(Ks0, Vt0, y0 + 256);
        tile(Ks1, Vt1);
        __syncthreads();
    }
#pragma unroll
    for (int r = 0; r < 4; r++) {
        float ls = lst[r];
#pragma unroll
        for (int off = 1; off < 16; off <<= 1)
            ls += __shfl_xor(ls, off);
        float inv = 1.f / ls;
        int row = n0 + fq * 4 + r;
#pragma unroll
        for (int nd = 0; nd < 2; nd++)
            o[((size_t)(b * NN) + row) * CCH + hh * HD + nd * 16 + fr] =
                f2bf(oacc[nd][r] * inv);
    }
}

// ---------------- depthwise 3x3 + bias + tanh-GELU, bf16 in/out ----------------
// 32-channel groups: LDS 20.7 KB -> 4 blocks/CU; grid = B * 16 tiles * 32 groups
__global__ __launch_bounds__(256, 4) void dwconv_gelu(const short* __restrict__ xf,
                                                      const float* __restrict__ pe_w,
                                                      const float* __restrict__ pe_b,
                                                      short* __restrict__ out) {
    int blk = blockIdx.x;
    int cg = blk & 31, sp = (blk >> 5) & 15, b = blk >> 9;
    int r0 = (sp >> 2) * 16, c0 = (sp & 3) * 16;
    int ch0 = cg * 32;
    int t = threadIdx.x;
    __shared__ short tile[18][18][32];
    for (int idx = t; idx < 18 * 18 * 4; idx += 256) {
        int pix = idx >> 2, part = idx & 3;
        int row = pix / 18, col = pix - row * 18;
        int gr = r0 + row - 1, gc = c0 + col - 1;
        bf16x8 v = {0, 0, 0, 0, 0, 0, 0, 0};
        if (gr >= 0 && gr < 64 && gc >= 0 && gc < 64)
            v = *(const bf16x8*)&xf[((size_t)(b * NN) + gr * GW + gc) * HIDN + ch0 + part * 8];
        *(bf16x8*)&tile[row][col][part * 8] = v;
    }
    __syncthreads();
    int cl = t & 31, sg = t >> 5;      // channel, row-group (8 groups x 2 rows)
    int ch = ch0 + cl;
    float wv[9];
#pragma unroll
    for (int k = 0; k < 9; k++) wv[k] = pe_w[ch * 9 + k];
    float bias = pe_b[ch];
#pragma unroll
    for (int q = 0; q < 2; q++) {
        int lr = sg * 2 + q;           // output row within tile; input rows lr..lr+2
        float cA[3], cB[3], cC[3];
#pragma unroll
        for (int ki = 0; ki < 3; ki++) {
            cA[ki] = bf2f(tile[lr + ki][0][cl]);
            cB[ki] = bf2f(tile[lr + ki][1][cl]);
        }
        for (int cc = 0; cc < 16; cc++) {
#pragma unroll
            for (int ki = 0; ki < 3; ki++) cC[ki] = bf2f(tile[lr + ki][cc + 2][cl]);
            float acc = bias;
#pragma unroll
            for (int ki = 0; ki < 3; ki++)
                acc += cA[ki] * wv[ki * 3] + cB[ki] * wv[ki * 3 + 1] + cC[ki] * wv[ki * 3 + 2];
            float z = 0.7978845608f * (acc + 0.044715f * acc * acc * acc);
            float e = __expf(-2.f * fabsf(z));
            float th = (1.f - e) / (1.f + e);
            th = (z < 0.f) ? -th : th;
            float gg = 0.5f * acc * (1.f + th);
            out[((size_t)(b * NN) + (r0 + lr) * GW + c0 + cc) * HIDN + ch] = f2bf(gg);
#pragma unroll
            for (int ki = 0; ki < 3; ki++) { cA[ki] = cB[ki]; cB[ki] = cC[ki]; }
        }
    }
}

extern "C" void kernel_launch(void* const* d_in, const int* in_sizes, int n_in,
                              void* d_out, int out_size, void* d_ws, size_t ws_size,
                              hipStream_t stream) {
    const float* x      = (const float*)d_in[0];
    const float* ln1_g  = (const float*)d_in[3];
    const float* ln1_b  = (const float*)d_in[4];
    const float* q_w    = (const float*)d_in[5];
    const float* kv_w   = (const float*)d_in[6];
    const float* sr_w   = (const float*)d_in[7];
    const float* sr_b   = (const float*)d_in[8];
    const float* srn_g  = (const float*)d_in[9];
    const float* srn_b  = (const float*)d_in[10];
    const float* proj_w = (const float*)d_in[11];
    const float* proj_b = (const float*)d_in[12];
    const float* ln2_g  = (const float*)d_in[13];
    const float* ln2_b  = (const float*)d_in[14];
    const float* fc1_w  = (const float*)d_in[15];
    const float* fc1_b  = (const float*)d_in[16];
    const float* pe_w   = (const float*)d_in[17];
    const float* pe_b   = (const float*)d_in[18];
    const float* fc2_w  = (const float*)d_in[19];
    const float* fc2_b  = (const float*)d_in[20];
    float* out = (float*)d_out;

    // workspace carve (bytes)
    char* base = (char*)d_ws;
    short* xn    = (short*)(base);                   // [0,4M)   xn / xn2 bf16
    short* qb    = (short*)(base + (4ull  << 20));   // [4,8)    q bf16 (pre-scaled)
    short* xbf   = (short*)(base + (8ull  << 20));   // [8,12)   x bf16 (residual copy)
    float* srtmp = (float*)(base + (12ull << 20));   // [12,14)  sr conv out f32 [2048][256]
    short* xkvn  = (short*)(base + (14ull << 20));   // [14,15)  x_kvn bf16
    short* kvk   = (short*)(base + (15ull << 20));   // [15,16)  k bf16 [2048][256]
    short* vtb   = (short*)(base + (17ull << 20));   // [17,18)  V^T bf16 [512][1024] (permuted)
    short* obf   = (short*)(base + (18ull << 20));   // [18,22)  attn out bf16
    short* x1    = (short*)(base + (22ull << 20));   // [22,26)  x1 bf16
    short* xf1   = (short*)(base + (30ull << 20));   // [30,46)  fc1 out bf16 [8192][1024]
    short* xf2g  = (short*)(base + (46ull << 20));   // [46,62)  gelu(dwconv) bf16
    short* qwb   = (short*)(base + (62ull << 20));   // weights bf16
    short* kvwb  = qwb  + 65536;
    short* pjwb  = kvwb + 131072;
    short* f1wb  = pjwb + 65536;
    short* f2wb  = f1wb + 262144;
    short* srwb  = f2wb + 262144;

    // 0. weights -> bf16 (sr reordered) + LN1+x->bf16 (wave), one launch
    prep_kernel<<<4096 + BB * NN / 4, 256, 0, stream>>>(
        q_w, kv_w, proj_w, fc1_w, fc2_w, sr_w,
        qwb, kvwb, pjwb, f1wb, f2wb, srwb,
        x, ln1_g, ln1_b, xn, xbf);
    // 2+3. q-GEMM and sr-GEMM merged
    qsr_gemm<<<768, 256, 0, stream>>>(xn, qwb, qb, srwb, sr_b, srtmp);
    // 3c. x_kvn = LN(srtmp)
    ln_wave<false><<<BB * NKV / 4, 256, 0, stream>>>(srtmp, srn_g, srn_b, xkvn);
    // 4. kv = x_kvn . kv_w^T -> kvk (k half) + vtb (v half, transposed+permuted)
    {
        dim3 g(512 / 64, (BB * NKV) / 64);
        kv_gemm<<<g, 256, 0, stream>>>(xkvn, kvwb, kvk, vtb);
    }
    // 5. attention -> obf (64 q rows/block, 4 blocks/CU)
    attn_mfma<<<BB * NH * (NN / 64), 256, 0, stream>>>(qb, kvk, vtb, obf);
    // 6. x1 = x + obf . proj_w^T + proj_b  (bf16 residual, bf16 out)
    {
        dim3 g(CCH / 64, (BB * NN) / 64);
        gemm64<true, 2><<<g, 256, 0, stream>>>(obf, pjwb, proj_b, xbf, x1, BB * NN, CCH, CCH);
    }
    // 7. xn2 = LN2(x1) (bf16 in, reuse xn)
    ln_wave<true><<<BB * NN / 4, 256, 0, stream>>>(x1, ln2_g, ln2_b, xn);
    // 8. xf1 = xn2 . fc1_w^T + fc1_b  (bf16 out, 128x128 tile)
    {
        dim3 g(HIDN / 128, (BB * NN) / 128);
        gemm_fc1<<<g, 256, 0, stream>>>(xn, f1wb, fc1_b, xf1, BB * NN, HIDN, CCH);
    }
    // 9. xf2g = gelu(dwconv3x3(xf1) + pe_b)  (32-ch groups, 4 blocks/CU)
    dwconv_gelu<<<BB * 512, 256, 0, stream>>>(xf1, pe_w, pe_b, xf2g);
    // 10. out = x1 + xf2g . fc2_w^T + fc2_b  (f32)
    {
        dim3 g(CCH / 64, (BB * NN) / 64);
        gemm64<false, 2><<<g, 256, 0, stream>>>(xf2g, f2wb, fc2_b, x1, out, BB * NN, CCH, HIDN);
    }
}